// Round 1
// baseline (4076.801 us; speedup 1.0000x reference)
//
#include <hip/hip_runtime.h>
#include <hip/hip_fp16.h>

#define NN 65536
#define NE 1048576
#define NB 64
#define HD 128
#define HD2 256
#define NHEAD 4
#define NPG 1024
#define BEPS 1e-5f

#define BM 64
#define BK 32
#define ASTR 68   // padded LDS stride for transposed A tile (272B: 16B-aligned, bank-skewed)

__device__ __forceinline__ float wsum64(float v) {
    #pragma unroll
    for (int m = 32; m > 0; m >>= 1) v += __shfl_xor(v, m, 64);
    return v;
}

__device__ __forceinline__ void atomAddF(float* p, float v) {
    unsafeAtomicAdd(p, v);
}

// ---------------- degrees ----------------
__global__ __launch_bounds__(256) void k_degrees(const int* __restrict__ src, const int* __restrict__ dst,
                                                 int* __restrict__ cnt_o, int* __restrict__ cnt_i) {
    int i = blockIdx.x * 256 + threadIdx.x;   // grid 1024 -> 262144 threads, 4 edges each
    #pragma unroll
    for (int j = 0; j < 4; ++j) {
        int e = i + j * (NE / 4);
        atomicAdd(&cnt_o[src[e]], 1);
        atomicAdd(&cnt_i[dst[e]], 1);
    }
}

__global__ __launch_bounds__(256) void k_degfin(const int* __restrict__ cnt_o, const int* __restrict__ cnt_i,
                                                float* __restrict__ dout_r, float* __restrict__ din_r) {
    int n = blockIdx.x * 256 + threadIdx.x;
    dout_r[n] = rsqrtf(fmaxf((float)cnt_o[n], 1.0f));
    din_r[n]  = rsqrtf(fmaxf((float)cnt_i[n], 1.0f));
}

// ---------------- init mean pooling ----------------
__global__ __launch_bounds__(128) void k_meanpool(const float* __restrict__ h, float* __restrict__ out_avg) {
    int g = blockIdx.x >> 3, chunk = blockIdx.x & 7, c = threadIdx.x;
    int r0 = g * NPG + chunk * 128;
    float s = 0.f;
    for (int r = r0; r < r0 + 128; ++r) s += h[(size_t)r * HD + c];
    atomAddF(&out_avg[g * HD + c], s * (1.0f / NPG));
}

// ---------------- BN column stats ----------------
__global__ __launch_bounds__(128) void k_colstats(const float* __restrict__ x,
                                                  float* __restrict__ colsum, float* __restrict__ colsq) {
    int c = threadIdx.x;
    int r0 = blockIdx.x * 64;     // grid 1024
    float s = 0.f, sq = 0.f;
    for (int r = r0; r < r0 + 64; ++r) {
        float v = x[(size_t)r * HD + c];
        s += v; sq += v * v;
    }
    atomAddF(&colsum[c], s);
    atomAddF(&colsq[c], sq);
}

__global__ __launch_bounds__(128) void k_bnparams(const float* __restrict__ colsum, const float* __restrict__ colsq,
                                                  const float* __restrict__ g, const float* __restrict__ b,
                                                  float* __restrict__ scale, float* __restrict__ shift) {
    int c = threadIdx.x;
    float mean = colsum[c] * (1.0f / NN);
    float var  = colsq[c] * (1.0f / NN) - mean * mean;
    float rstd = rsqrtf(var + BEPS);
    float sc = rstd * g[c];
    scale[c] = sc;
    shift[c] = b[c] - mean * sc;
}

// ---------------- edge gather + normalize + scatter-add ----------------
__global__ __launch_bounds__(256) void k_scatter(const float* __restrict__ x,
                                                 const float* __restrict__ scale, const float* __restrict__ shift,
                                                 const float* __restrict__ dout_r,
                                                 const int* __restrict__ src, const int* __restrict__ dst,
                                                 float* __restrict__ agg) {
    int t = threadIdx.x;
    int e = blockIdx.x * 8 + (t >> 5);
    int c4 = (t & 31) * 4;
    int s = src[e], d = dst[e];
    float dr = dout_r[s];
    const float4 xv = *(const float4*)(x + (size_t)s * HD + c4);
    const float4 sc = *(const float4*)(scale + c4);
    const float4 sh = *(const float4*)(shift + c4);
    float* o = agg + (size_t)d * HD + c4;
    atomAddF(o + 0, (xv.x * sc.x + sh.x) * dr);
    atomAddF(o + 1, (xv.y * sc.y + sh.y) * dr);
    atomAddF(o + 2, (xv.z * sc.z + sh.z) * dr);
    atomAddF(o + 3, (xv.w * sc.w + sh.w) * dr);
}

// ---------------- gconv GEMM: out = res + relu((agg*din_r) @ W + b) ----------------
__global__ __launch_bounds__(256) void k_gconv(const float* __restrict__ A, const float* __restrict__ dinr,
                                               const float* __restrict__ W, const float* __restrict__ bias,
                                               const float* __restrict__ res, float* __restrict__ outp) {
    __shared__ float As[BK * ASTR];
    __shared__ float Ws[BK * HD];
    const int tid = threadIdx.x;
    const int row0 = blockIdx.x * BM;
    const int tr = tid >> 5, tc = tid & 31;
    float acc[8][4] = {};
    for (int kc = 0; kc < HD; kc += BK) {
        #pragma unroll
        for (int i = 0; i < 2; ++i) {
            int idx = tid * 2 + i;
            int r = idx >> 3, kq = idx & 7;
            float4 v = *(const float4*)(A + (size_t)(row0 + r) * HD + kc + kq * 4);
            float dr = dinr[row0 + r];
            As[(kq * 4 + 0) * ASTR + r] = v.x * dr;
            As[(kq * 4 + 1) * ASTR + r] = v.y * dr;
            As[(kq * 4 + 2) * ASTR + r] = v.z * dr;
            As[(kq * 4 + 3) * ASTR + r] = v.w * dr;
        }
        #pragma unroll
        for (int i = 0; i < 4; ++i) {
            int idx = tid + i * 256;
            int kr = idx >> 5, cq = idx & 31;
            *(float4*)(Ws + kr * HD + cq * 4) = *(const float4*)(W + (size_t)(kc + kr) * HD + cq * 4);
        }
        __syncthreads();
        #pragma unroll 4
        for (int k = 0; k < BK; ++k) {
            const float4 a0 = *(const float4*)(As + k * ASTR + tr * 8);
            const float4 a1 = *(const float4*)(As + k * ASTR + tr * 8 + 4);
            const float4 w  = *(const float4*)(Ws + k * HD + tc * 4);
            float av[8] = {a0.x, a0.y, a0.z, a0.w, a1.x, a1.y, a1.z, a1.w};
            #pragma unroll
            for (int r = 0; r < 8; ++r) {
                acc[r][0] += av[r] * w.x; acc[r][1] += av[r] * w.y;
                acc[r][2] += av[r] * w.z; acc[r][3] += av[r] * w.w;
            }
        }
        __syncthreads();
    }
    const float4 bv = *(const float4*)(bias + tc * 4);
    #pragma unroll
    for (int r = 0; r < 8; ++r) {
        int row = row0 + tr * 8 + r;
        const float4 rv = *(const float4*)(res + (size_t)row * HD + tc * 4);
        float4 o;
        o.x = rv.x + fmaxf(acc[r][0] + bv.x, 0.f);
        o.y = rv.y + fmaxf(acc[r][1] + bv.y, 0.f);
        o.z = rv.z + fmaxf(acc[r][2] + bv.z, 0.f);
        o.w = rv.w + fmaxf(acc[r][3] + bv.w, 0.f);
        *(float4*)(outp + (size_t)row * HD + tc * 4) = o;
    }
}

// ---------------- attention precomputes ----------------
__global__ __launch_bounds__(128) void k_kvec(const float* __restrict__ interf, const float* __restrict__ Wk,
                                              float* __restrict__ kvec) {
    int hb = blockIdx.x;            // h*64+g
    int hh = hb >> 6, g = hb & 63;
    int o = threadIdx.x;
    __shared__ float f[HD];
    f[o] = interf[g * HD + o];
    __syncthreads();
    const float* Wkh = Wk + (size_t)hh * HD * HD;
    float s = 0.f;
    for (int d = 0; d < HD; ++d) s += f[d] * Wkh[(size_t)d * HD + o];
    kvec[hb * HD + o] = s;
}

__global__ __launch_bounds__(128) void k_watt(const float* __restrict__ Wq, const float* __restrict__ kvec,
                                              float* __restrict__ watt) {
    int hb = blockIdx.x;
    int hh = hb >> 6;
    int d = threadIdx.x;
    __shared__ float kv[HD];
    kv[d] = kvec[hb * HD + d];
    __syncthreads();
    const float* row = Wq + ((size_t)hh * HD + d) * HD;
    float s = 0.f;
    #pragma unroll 4
    for (int o = 0; o < HD; o += 4) {
        float4 w = *(const float4*)(row + o);
        s += w.x * kv[o] + w.y * kv[o + 1] + w.z * kv[o + 2] + w.w * kv[o + 3];
    }
    watt[hb * HD + d] = s * 0.027950849718747373f;   // 1/sqrt(1280)
}

__global__ __launch_bounds__(256) void k_U(const float* __restrict__ Wv, const float* __restrict__ Wc,
                                           float* __restrict__ Umat) {
    int idx = blockIdx.x * 256 + threadIdx.x;   // 65536 threads
    int o = idx & 127;
    int d = (idx >> 7) & 127;
    int hh = idx >> 14;
    const float* wv = Wv + ((size_t)hh * HD + d) * HD;
    const float* wc = Wc + (size_t)(hh * HD) * HD + o;
    float s = 0.f;
    for (int m = 0; m < HD; ++m) s += wv[m] * wc[(size_t)m * HD];
    Umat[idx] = s;
}

// ---------------- attention scores ----------------
__global__ __launch_bounds__(256) void k_scores(const float* __restrict__ h2, const float* __restrict__ watt,
                                                float* __restrict__ att) {
    int tid = threadIdx.x;
    int lane = tid & 63;
    int n = blockIdx.x * 4 + (tid >> 6);
    int g = n >> 10;
    float2 x = *(const float2*)(h2 + (size_t)n * HD + lane * 2);
    #pragma unroll
    for (int hh = 0; hh < NHEAD; ++hh) {
        float2 w = *(const float2*)(watt + ((size_t)(hh * NB + g)) * HD + lane * 2);
        float p = x.x * w.x + x.y * w.y;
        p = wsum64(p);
        if (lane == 0) att[(size_t)hh * NN + n] = p;
    }
}

// ---------------- segment softmax ----------------
__global__ __launch_bounds__(256) void k_segsoftmax(const float* __restrict__ att, float* __restrict__ alpha) {
    const int hh = blockIdx.x >> 6, g = blockIdx.x & 63;
    const int t = threadIdx.x;
    const float* a = att + (size_t)hh * NN + g * NPG;
    float* al = alpha + (size_t)hh * NN + g * NPG;
    float v[4]; float mx = -1e30f;
    #pragma unroll
    for (int i = 0; i < 4; ++i) { v[i] = a[t + i * 256]; mx = fmaxf(mx, v[i]); }
    #pragma unroll
    for (int m = 32; m > 0; m >>= 1) mx = fmaxf(mx, __shfl_xor(mx, m, 64));
    __shared__ float redm[4], reds[4];
    if ((t & 63) == 0) redm[t >> 6] = mx;
    __syncthreads();
    mx = fmaxf(fmaxf(redm[0], redm[1]), fmaxf(redm[2], redm[3]));
    float s = 0.f;
    #pragma unroll
    for (int i = 0; i < 4; ++i) { v[i] = __expf(v[i] - mx); s += v[i]; }
    s = wsum64(s);
    if ((t & 63) == 0) reds[t >> 6] = s;
    __syncthreads();
    s = reds[0] + reds[1] + reds[2] + reds[3];
    float inv = 1.f / s;
    #pragma unroll
    for (int i = 0; i < 4; ++i) al[t + i * 256] = v[i] * inv;
}

// ---------------- mo = sum_h alpha_h * (h2 @ U_h) ----------------
__global__ __launch_bounds__(256) void k_mo(const float* __restrict__ h2, const float* __restrict__ Umat,
                                            const float* __restrict__ alpha, float* __restrict__ mo) {
    __shared__ float As[HD * ASTR];   // full-K A tile, staged once
    __shared__ float Ws[BK * HD];
    const int tid = threadIdx.x;
    const int row0 = blockIdx.x * BM;
    const int tr = tid >> 5, tc = tid & 31;
    #pragma unroll
    for (int i = 0; i < 8; ++i) {
        int idx = tid + i * 256;
        int r = idx >> 5, kq = idx & 31;
        float4 v = *(const float4*)(h2 + (size_t)(row0 + r) * HD + kq * 4);
        As[(kq * 4 + 0) * ASTR + r] = v.x;
        As[(kq * 4 + 1) * ASTR + r] = v.y;
        As[(kq * 4 + 2) * ASTR + r] = v.z;
        As[(kq * 4 + 3) * ASTR + r] = v.w;
    }
    float moacc[8][4] = {};
    for (int hh = 0; hh < NHEAD; ++hh) {
        const float* Uh = Umat + (size_t)hh * HD * HD;
        float acc[8][4] = {};
        for (int kc = 0; kc < HD; kc += BK) {
            #pragma unroll
            for (int i = 0; i < 4; ++i) {
                int idx = tid + i * 256;
                int kr = idx >> 5, cq = idx & 31;
                *(float4*)(Ws + kr * HD + cq * 4) = *(const float4*)(Uh + (size_t)(kc + kr) * HD + cq * 4);
            }
            __syncthreads();
            #pragma unroll 4
            for (int k = 0; k < BK; ++k) {
                const float4 a0 = *(const float4*)(As + (kc + k) * ASTR + tr * 8);
                const float4 a1 = *(const float4*)(As + (kc + k) * ASTR + tr * 8 + 4);
                const float4 w  = *(const float4*)(Ws + k * HD + tc * 4);
                float av[8] = {a0.x, a0.y, a0.z, a0.w, a1.x, a1.y, a1.z, a1.w};
                #pragma unroll
                for (int r = 0; r < 8; ++r) {
                    acc[r][0] += av[r] * w.x; acc[r][1] += av[r] * w.y;
                    acc[r][2] += av[r] * w.z; acc[r][3] += av[r] * w.w;
                }
            }
            __syncthreads();
        }
        #pragma unroll
        for (int r = 0; r < 8; ++r) {
            float al = alpha[(size_t)hh * NN + row0 + tr * 8 + r];
            moacc[r][0] += al * acc[r][0]; moacc[r][1] += al * acc[r][1];
            moacc[r][2] += al * acc[r][2]; moacc[r][3] += al * acc[r][3];
        }
    }
    #pragma unroll
    for (int r = 0; r < 8; ++r) {
        int row = row0 + tr * 8 + r;
        *(float4*)(mo + (size_t)row * HD + tc * 4) = make_float4(moacc[r][0], moacc[r][1], moacc[r][2], moacc[r][3]);
    }
}

// ---------------- x1 = LN(mo + h2) ----------------
__global__ __launch_bounds__(256) void k_x1ln(const float* __restrict__ mo, const float* __restrict__ h2,
                                              const float* __restrict__ g, const float* __restrict__ b,
                                              float* __restrict__ x1) {
    int tid = threadIdx.x;
    int lane = tid & 63;
    int n = blockIdx.x * 4 + (tid >> 6);
    float2 m = *(const float2*)(mo + (size_t)n * HD + lane * 2);
    float2 hh = *(const float2*)(h2 + (size_t)n * HD + lane * 2);
    float a0 = m.x + hh.x, a1 = m.y + hh.y;
    float s = a0 + a1, sq = a0 * a0 + a1 * a1;
    #pragma unroll
    for (int mm = 32; mm > 0; mm >>= 1) { s += __shfl_xor(s, mm, 64); sq += __shfl_xor(sq, mm, 64); }
    float mean = s * (1.f / HD);
    float var  = sq * (1.f / HD) - mean * mean;
    float rstd = rsqrtf(var + BEPS);
    float2 gg = *(const float2*)(g + lane * 2);
    float2 bb = *(const float2*)(b + lane * 2);
    float2 o;
    o.x = (a0 - mean) * rstd * gg.x + bb.x;
    o.y = (a1 - mean) * rstd * gg.y + bb.y;
    *(float2*)(x1 + (size_t)n * HD + lane * 2) = o;
}

// ---------------- FFN1: mid = relu(x1 @ Wf1 + bf1), fp16 out ----------------
__global__ __launch_bounds__(256) void k_ffn1(const float* __restrict__ X, const float* __restrict__ W,
                                              const float* __restrict__ bias, __half* __restrict__ midp) {
    __shared__ float As[BK * ASTR];
    __shared__ float Ws[BK * HD];
    const int tid = threadIdx.x;
    const int row0 = (blockIdx.x >> 1) * BM;
    const int c0 = (blockIdx.x & 1) * 128;
    const int tr = tid >> 5, tc = tid & 31;
    float acc[8][4] = {};
    for (int kc = 0; kc < HD; kc += BK) {
        #pragma unroll
        for (int i = 0; i < 2; ++i) {
            int idx = tid * 2 + i;
            int r = idx >> 3, kq = idx & 7;
            float4 v = *(const float4*)(X + (size_t)(row0 + r) * HD + kc + kq * 4);
            As[(kq * 4 + 0) * ASTR + r] = v.x;
            As[(kq * 4 + 1) * ASTR + r] = v.y;
            As[(kq * 4 + 2) * ASTR + r] = v.z;
            As[(kq * 4 + 3) * ASTR + r] = v.w;
        }
        #pragma unroll
        for (int i = 0; i < 4; ++i) {
            int idx = tid + i * 256;
            int kr = idx >> 5, cq = idx & 31;
            *(float4*)(Ws + kr * HD + cq * 4) = *(const float4*)(W + (size_t)(kc + kr) * HD2 + c0 + cq * 4);
        }
        __syncthreads();
        #pragma unroll 4
        for (int k = 0; k < BK; ++k) {
            const float4 a0 = *(const float4*)(As + k * ASTR + tr * 8);
            const float4 a1 = *(const float4*)(As + k * ASTR + tr * 8 + 4);
            const float4 w  = *(const float4*)(Ws + k * HD + tc * 4);
            float av[8] = {a0.x, a0.y, a0.z, a0.w, a1.x, a1.y, a1.z, a1.w};
            #pragma unroll
            for (int r = 0; r < 8; ++r) {
                acc[r][0] += av[r] * w.x; acc[r][1] += av[r] * w.y;
                acc[r][2] += av[r] * w.z; acc[r][3] += av[r] * w.w;
            }
        }
        __syncthreads();
    }
    const float4 bv = *(const float4*)(bias + c0 + tc * 4);
    #pragma unroll
    for (int r = 0; r < 8; ++r) {
        int row = row0 + tr * 8 + r;
        float v0 = fmaxf(acc[r][0] + bv.x, 0.f);
        float v1 = fmaxf(acc[r][1] + bv.y, 0.f);
        float v2 = fmaxf(acc[r][2] + bv.z, 0.f);
        float v3 = fmaxf(acc[r][3] + bv.w, 0.f);
        __half* base = midp + (size_t)row * HD2 + c0 + tc * 4;
        *(__half2*)(base)     = __floats2half2_rn(v0, v1);
        *(__half2*)(base + 2) = __floats2half2_rn(v2, v3);
    }
}

// ---------------- FFN2 + LN + fused graph readout ----------------
__global__ __launch_bounds__(256) void k_ffn2(const __half* __restrict__ midp, const float* __restrict__ W,
                                              const float* __restrict__ bias, const float* __restrict__ x1,
                                              const float* __restrict__ lng, const float* __restrict__ lnb,
                                              float* __restrict__ outp) {
    __shared__ float As[BK * ASTR];
    __shared__ float Ws[BK * HD];
    __shared__ float cred[8 * HD];
    const int tid = threadIdx.x;
    const int row0 = blockIdx.x * BM;
    const int tr = tid >> 5, tc = tid & 31;
    float acc[8][4] = {};
    for (int kc = 0; kc < HD2; kc += BK) {
        {
            int r = tid >> 2, kq = tid & 3;
            union { uint4 u4; __half2 h2v[4]; } uu;
            uu.u4 = *(const uint4*)(midp + (size_t)(row0 + r) * HD2 + kc + kq * 8);
            #pragma unroll
            for (int u = 0; u < 4; ++u) {
                As[(kq * 8 + u * 2 + 0) * ASTR + r] = __low2float(uu.h2v[u]);
                As[(kq * 8 + u * 2 + 1) * ASTR + r] = __high2float(uu.h2v[u]);
            }
        }
        #pragma unroll
        for (int i = 0; i < 4; ++i) {
            int idx = tid + i * 256;
            int kr = idx >> 5, cq = idx & 31;
            *(float4*)(Ws + kr * HD + cq * 4) = *(const float4*)(W + (size_t)(kc + kr) * HD + cq * 4);
        }
        __syncthreads();
        #pragma unroll 4
        for (int k = 0; k < BK; ++k) {
            const float4 a0 = *(const float4*)(As + k * ASTR + tr * 8);
            const float4 a1 = *(const float4*)(As + k * ASTR + tr * 8 + 4);
            const float4 w  = *(const float4*)(Ws + k * HD + tc * 4);
            float av[8] = {a0.x, a0.y, a0.z, a0.w, a1.x, a1.y, a1.z, a1.w};
            #pragma unroll
            for (int r = 0; r < 8; ++r) {
                acc[r][0] += av[r] * w.x; acc[r][1] += av[r] * w.y;
                acc[r][2] += av[r] * w.z; acc[r][3] += av[r] * w.w;
            }
        }
        __syncthreads();
    }
    const float4 bv  = *(const float4*)(bias + tc * 4);
    const float4 gv  = *(const float4*)(lng + tc * 4);
    const float4 bbv = *(const float4*)(lnb + tc * 4);
    float csum0 = 0.f, csum1 = 0.f, csum2 = 0.f, csum3 = 0.f;
    #pragma unroll
    for (int r = 0; r < 8; ++r) {
        int row = row0 + tr * 8 + r;
        const float4 xv = *(const float4*)(x1 + (size_t)row * HD + tc * 4);
        float v0 = acc[r][0] + bv.x + xv.x;
        float v1 = acc[r][1] + bv.y + xv.y;
        float v2 = acc[r][2] + bv.z + xv.z;
        float v3 = acc[r][3] + bv.w + xv.w;
        float s  = v0 + v1 + v2 + v3;
        float sq = v0 * v0 + v1 * v1 + v2 * v2 + v3 * v3;
        #pragma unroll
        for (int m = 1; m <= 16; m <<= 1) {
            s  += __shfl_xor(s, m, 64);
            sq += __shfl_xor(sq, m, 64);
        }
        float mean = s * (1.f / HD);
        float var  = sq * (1.f / HD) - mean * mean;
        float rstd = rsqrtf(var + BEPS);
        v0 = (v0 - mean) * rstd * gv.x + bbv.x;
        v1 = (v1 - mean) * rstd * gv.y + bbv.y;
        v2 = (v2 - mean) * rstd * gv.z + bbv.z;
        v3 = (v3 - mean) * rstd * gv.w + bbv.w;
        csum0 += v0; csum1 += v1; csum2 += v2; csum3 += v3;
    }
    *(float4*)(cred + tr * HD + tc * 4) = make_float4(csum0, csum1, csum2, csum3);
    __syncthreads();
    if (tid < HD) {
        float s = 0.f;
        #pragma unroll
        for (int t = 0; t < 8; ++t) s += cred[t * HD + tid];
        int g = row0 >> 10;           // BM=64 divides 1024 -> whole block in one graph
        atomAddF(&outp[g * HD + tid], s);
    }
}

extern "C" void kernel_launch(void* const* d_in, const int* in_sizes, int n_in,
                              void* d_out, int out_size, void* d_ws, size_t ws_size,
                              hipStream_t stream) {
    (void)in_sizes; (void)n_in; (void)out_size;
    const float* h      = (const float*)d_in[0];
    const float* interf = (const float*)d_in[1];
    const float* gamma1 = (const float*)d_in[2];
    const float* beta1  = (const float*)d_in[3];
    const float* W1     = (const float*)d_in[4];
    const float* b1     = (const float*)d_in[5];
    const float* gamma2 = (const float*)d_in[6];
    const float* beta2  = (const float*)d_in[7];
    const float* W2     = (const float*)d_in[8];
    const float* b2     = (const float*)d_in[9];
    const float* Wq     = (const float*)d_in[10];
    const float* Wk     = (const float*)d_in[11];
    const float* Wv     = (const float*)d_in[12];
    const float* Wc     = (const float*)d_in[13];
    const float* ln_g   = (const float*)d_in[14];
    const float* ln_b   = (const float*)d_in[15];
    const float* Wf1    = (const float*)d_in[16];
    const float* bf1    = (const float*)d_in[17];
    const float* Wf2    = (const float*)d_in[18];
    const float* bf2    = (const float*)d_in[19];
    const int*   src    = (const int*)d_in[20];
    const int*   dst    = (const int*)d_in[21];
    // d_in[22] graph_id unused: graphs are contiguous blocks of 1024 nodes

    float* out = (float*)d_out;            // [0:8192) readout, [8192:16384) init_avg_h
    float* P   = (float*)d_ws;             // 32 MB: agg1/agg2 -> mo
    float* Q   = P + 8388608;              // 32 MB: h1 -> x1
    float* Rf  = Q + 8388608;              // 32 MB: h2 -> mid(fp16)
    __half* mid = (__half*)Rf;
    float* aux  = Rf + 8388608;
    float* dout_r = aux;
    float* din_r  = aux + 65536;
    int*   cnt_o  = (int*)(aux + 131072);
    int*   cnt_i  = (int*)(aux + 196608);
    float* colsum = aux + 262144;
    float* colsq  = colsum + 128;
    float* bscale = colsq + 128;
    float* bshift = bscale + 128;
    float* kvec   = bshift + 128;
    float* watt   = kvec + 32768;
    float* Umat   = watt + 32768;
    float* att    = Umat + 65536;
    float* alpha  = att + 262144;

    if (ws_size < (size_t)(8388608 * 3 + 918016) * 4) return;   // need ~104 MB scratch

    hipMemsetAsync(out, 0, 16384 * 4, stream);
    hipMemsetAsync(cnt_o, 0, 65536 * 4 * 2, stream);
    k_degrees<<<1024, 256, 0, stream>>>(src, dst, cnt_o, cnt_i);
    k_degfin<<<256, 256, 0, stream>>>(cnt_o, cnt_i, dout_r, din_r);
    k_meanpool<<<512, 128, 0, stream>>>(h, out + 8192);

    // gconv block 1
    hipMemsetAsync(colsum, 0, 256 * 4, stream);
    k_colstats<<<1024, 128, 0, stream>>>(h, colsum, colsq);
    k_bnparams<<<1, 128, 0, stream>>>(colsum, colsq, gamma1, beta1, bscale, bshift);
    hipMemsetAsync(P, 0, (size_t)8388608 * 4, stream);
    k_scatter<<<131072, 256, 0, stream>>>(h, bscale, bshift, dout_r, src, dst, P);
    k_gconv<<<1024, 256, 0, stream>>>(P, din_r, W1, b1, h, Q);

    // gconv block 2
    hipMemsetAsync(colsum, 0, 256 * 4, stream);
    k_colstats<<<1024, 128, 0, stream>>>(Q, colsum, colsq);
    k_bnparams<<<1, 128, 0, stream>>>(colsum, colsq, gamma2, beta2, bscale, bshift);
    hipMemsetAsync(P, 0, (size_t)8388608 * 4, stream);
    k_scatter<<<131072, 256, 0, stream>>>(Q, bscale, bshift, dout_r, src, dst, P);
    k_gconv<<<1024, 256, 0, stream>>>(P, din_r, W2, b2, Q, Rf);

    // attention
    k_kvec<<<256, 128, 0, stream>>>(interf, Wk, kvec);
    k_watt<<<256, 128, 0, stream>>>(Wq, kvec, watt);
    k_U<<<256, 256, 0, stream>>>(Wv, Wc, Umat);
    k_scores<<<16384, 256, 0, stream>>>(Rf, watt, att);
    k_segsoftmax<<<256, 256, 0, stream>>>(att, alpha);
    k_mo<<<1024, 256, 0, stream>>>(Rf, Umat, alpha, P);
    k_x1ln<<<16384, 256, 0, stream>>>(P, Rf, ln_g, ln_b, Q);

    // FFN + fused readout
    k_ffn1<<<2048, 256, 0, stream>>>(Q, Wf1, bf1, mid);
    k_ffn2<<<1024, 256, 0, stream>>>(mid, Wf2, bf2, Q, ln_g, ln_b, out);
}

// Round 2
// 826.008 us; speedup vs baseline: 4.9355x; 4.9355x over previous
//
#include <hip/hip_runtime.h>
#include <hip/hip_fp16.h>

#define NN 65536
#define NE 1048576
#define NB 64
#define HD 128
#define HD2 256
#define NHEAD 4
#define NPG 1024
#define BEPS 1e-5f

#define BM 64
#define BK 32
#define ASTR 68   // padded LDS stride for transposed A tile

__device__ __forceinline__ float wsum64(float v) {
    #pragma unroll
    for (int m = 32; m > 0; m >>= 1) v += __shfl_xor(v, m, 64);
    return v;
}

__device__ __forceinline__ void atomAddF(float* p, float v) {
    unsafeAtomicAdd(p, v);
}

// ---------------- degrees ----------------
__global__ __launch_bounds__(256) void k_degrees(const int* __restrict__ src, const int* __restrict__ dst,
                                                 int* __restrict__ cnt_o, int* __restrict__ cnt_i) {
    int i = blockIdx.x * 256 + threadIdx.x;
    #pragma unroll
    for (int j = 0; j < 4; ++j) {
        int e = i + j * (NE / 4);
        atomicAdd(&cnt_o[src[e]], 1);
        atomicAdd(&cnt_i[dst[e]], 1);
    }
}

__global__ __launch_bounds__(256) void k_degfin(const int* __restrict__ cnt_o, const int* __restrict__ cnt_i,
                                                float* __restrict__ dout_r, float* __restrict__ din_r) {
    int n = blockIdx.x * 256 + threadIdx.x;
    dout_r[n] = rsqrtf(fmaxf((float)cnt_o[n], 1.0f));
    din_r[n]  = rsqrtf(fmaxf((float)cnt_i[n], 1.0f));
}

// ---------------- CSR build: scan + fill ----------------
__global__ __launch_bounds__(1024) void k_scan(const int* __restrict__ cnt, int* __restrict__ offs,
                                               int* __restrict__ cursor) {
    __shared__ int sums[1024];
    const int t = threadIdx.x;
    const int base = t * 64;
    int s = 0;
    #pragma unroll 8
    for (int i = 0; i < 64; ++i) s += cnt[base + i];
    sums[t] = s;
    __syncthreads();
    int x = s;
    #pragma unroll
    for (int off = 1; off < 1024; off <<= 1) {
        int v = (t >= off) ? sums[t - off] : 0;
        __syncthreads();
        x += v; sums[t] = x;
        __syncthreads();
    }
    int run = x - s;   // exclusive prefix
    #pragma unroll 8
    for (int i = 0; i < 64; ++i) {
        offs[base + i] = run;
        cursor[base + i] = run;
        run += cnt[base + i];
    }
    if (t == 1023) offs[NN] = run;
}

__global__ __launch_bounds__(256) void k_fill(const int* __restrict__ src, const int* __restrict__ dst,
                                              int* __restrict__ cursor, int* __restrict__ elist) {
    int i = blockIdx.x * 256 + threadIdx.x;
    #pragma unroll
    for (int j = 0; j < 4; ++j) {
        int e = i + j * (NE / 4);
        int pos = atomicAdd(&cursor[dst[e]], 1);
        elist[pos] = src[e];
    }
}

// ---------------- init mean pooling ----------------
__global__ __launch_bounds__(128) void k_meanpool(const float* __restrict__ h, float* __restrict__ out_avg) {
    int g = blockIdx.x >> 3, chunk = blockIdx.x & 7, c = threadIdx.x;
    int r0 = g * NPG + chunk * 128;
    float s = 0.f;
    for (int r = r0; r < r0 + 128; ++r) s += h[(size_t)r * HD + c];
    atomAddF(&out_avg[g * HD + c], s * (1.0f / NPG));
}

// ---------------- BN column stats ----------------
__global__ __launch_bounds__(128) void k_colstats(const float* __restrict__ x,
                                                  float* __restrict__ colsum, float* __restrict__ colsq) {
    int c = threadIdx.x;
    int r0 = blockIdx.x * 64;
    float s = 0.f, sq = 0.f;
    for (int r = r0; r < r0 + 64; ++r) {
        float v = x[(size_t)r * HD + c];
        s += v; sq += v * v;
    }
    atomAddF(&colsum[c], s);
    atomAddF(&colsq[c], sq);
}

__global__ __launch_bounds__(128) void k_bnparams(const float* __restrict__ colsum, const float* __restrict__ colsq,
                                                  const float* __restrict__ g, const float* __restrict__ b,
                                                  float* __restrict__ scale, float* __restrict__ shift) {
    int c = threadIdx.x;
    float mean = colsum[c] * (1.0f / NN);
    float var  = colsq[c] * (1.0f / NN) - mean * mean;
    float rstd = rsqrtf(var + BEPS);
    float sc = rstd * g[c];
    scale[c] = sc;
    shift[c] = b[c] - mean * sc;
}

// ---------------- CSR aggregation: agg[d] = din_r[d] * sum_{s in N(d)} (x[s]*sc+sh)*dout_r[s] ----------------
__global__ __launch_bounds__(256) void k_aggregate(const float* __restrict__ x,
                                                   const float* __restrict__ scale, const float* __restrict__ shift,
                                                   const float* __restrict__ dout_r, const float* __restrict__ din_r,
                                                   const int* __restrict__ offs, const int* __restrict__ elist,
                                                   float* __restrict__ agg) {
    const int tid = threadIdx.x;
    const int node = blockIdx.x * 4 + (tid >> 6);
    const int lane = tid & 63;
    const int half = lane >> 5;
    const int c4 = (lane & 31) * 4;
    const float4 sc = *(const float4*)(scale + c4);
    const float4 sh = *(const float4*)(shift + c4);
    const int beg = offs[node], end = offs[node + 1];
    float a0 = 0.f, a1 = 0.f, a2 = 0.f, a3 = 0.f;
    for (int i = beg + half; i < end; i += 2) {
        int s = elist[i];
        float dr = dout_r[s];
        const float4 v = *(const float4*)(x + (size_t)s * HD + c4);
        a0 += (v.x * sc.x + sh.x) * dr;
        a1 += (v.y * sc.y + sh.y) * dr;
        a2 += (v.z * sc.z + sh.z) * dr;
        a3 += (v.w * sc.w + sh.w) * dr;
    }
    a0 += __shfl_xor(a0, 32, 64);
    a1 += __shfl_xor(a1, 32, 64);
    a2 += __shfl_xor(a2, 32, 64);
    a3 += __shfl_xor(a3, 32, 64);
    if (half == 0) {
        float dn = din_r[node];
        *(float4*)(agg + (size_t)node * HD + c4) = make_float4(a0 * dn, a1 * dn, a2 * dn, a3 * dn);
    }
}

// ---------------- gconv GEMM: out = res + relu(agg @ W + b) ----------------
__global__ __launch_bounds__(256) void k_gconv(const float* __restrict__ A,
                                               const float* __restrict__ W, const float* __restrict__ bias,
                                               const float* __restrict__ res, float* __restrict__ outp) {
    __shared__ float As[BK * ASTR];
    __shared__ float Ws[BK * HD];
    const int tid = threadIdx.x;
    const int row0 = blockIdx.x * BM;
    const int tr = tid >> 5, tc = tid & 31;
    float acc[8][4] = {};
    for (int kc = 0; kc < HD; kc += BK) {
        #pragma unroll
        for (int i = 0; i < 2; ++i) {
            int idx = tid * 2 + i;
            int r = idx >> 3, kq = idx & 7;
            float4 v = *(const float4*)(A + (size_t)(row0 + r) * HD + kc + kq * 4);
            As[(kq * 4 + 0) * ASTR + r] = v.x;
            As[(kq * 4 + 1) * ASTR + r] = v.y;
            As[(kq * 4 + 2) * ASTR + r] = v.z;
            As[(kq * 4 + 3) * ASTR + r] = v.w;
        }
        #pragma unroll
        for (int i = 0; i < 4; ++i) {
            int idx = tid + i * 256;
            int kr = idx >> 5, cq = idx & 31;
            *(float4*)(Ws + kr * HD + cq * 4) = *(const float4*)(W + (size_t)(kc + kr) * HD + cq * 4);
        }
        __syncthreads();
        #pragma unroll 4
        for (int k = 0; k < BK; ++k) {
            const float4 a0 = *(const float4*)(As + k * ASTR + tr * 8);
            const float4 a1 = *(const float4*)(As + k * ASTR + tr * 8 + 4);
            const float4 w  = *(const float4*)(Ws + k * HD + tc * 4);
            float av[8] = {a0.x, a0.y, a0.z, a0.w, a1.x, a1.y, a1.z, a1.w};
            #pragma unroll
            for (int r = 0; r < 8; ++r) {
                acc[r][0] += av[r] * w.x; acc[r][1] += av[r] * w.y;
                acc[r][2] += av[r] * w.z; acc[r][3] += av[r] * w.w;
            }
        }
        __syncthreads();
    }
    const float4 bv = *(const float4*)(bias + tc * 4);
    #pragma unroll
    for (int r = 0; r < 8; ++r) {
        int row = row0 + tr * 8 + r;
        const float4 rv = *(const float4*)(res + (size_t)row * HD + tc * 4);
        float4 o;
        o.x = rv.x + fmaxf(acc[r][0] + bv.x, 0.f);
        o.y = rv.y + fmaxf(acc[r][1] + bv.y, 0.f);
        o.z = rv.z + fmaxf(acc[r][2] + bv.z, 0.f);
        o.w = rv.w + fmaxf(acc[r][3] + bv.w, 0.f);
        *(float4*)(outp + (size_t)row * HD + tc * 4) = o;
    }
}

// ---------------- attention precomputes ----------------
__global__ __launch_bounds__(128) void k_kvec(const float* __restrict__ interf, const float* __restrict__ Wk,
                                              float* __restrict__ kvec) {
    int hb = blockIdx.x;            // h*64+g
    int hh = hb >> 6, g = hb & 63;
    int o = threadIdx.x;
    __shared__ float f[HD];
    f[o] = interf[g * HD + o];
    __syncthreads();
    const float* Wkh = Wk + (size_t)hh * HD * HD;
    float s = 0.f;
    for (int d = 0; d < HD; ++d) s += f[d] * Wkh[(size_t)d * HD + o];
    kvec[hb * HD + o] = s;
}

__global__ __launch_bounds__(128) void k_watt(const float* __restrict__ Wq, const float* __restrict__ kvec,
                                              float* __restrict__ watt) {
    int hb = blockIdx.x;
    int hh = hb >> 6;
    int d = threadIdx.x;
    __shared__ float kv[HD];
    kv[d] = kvec[hb * HD + d];
    __syncthreads();
    const float* row = Wq + ((size_t)hh * HD + d) * HD;
    float s = 0.f;
    #pragma unroll 4
    for (int o = 0; o < HD; o += 4) {
        float4 w = *(const float4*)(row + o);
        s += w.x * kv[o] + w.y * kv[o + 1] + w.z * kv[o + 2] + w.w * kv[o + 3];
    }
    watt[hb * HD + d] = s * 0.027950849718747373f;   // 1/sqrt(1280)
}

__global__ __launch_bounds__(256) void k_U(const float* __restrict__ Wv, const float* __restrict__ Wc,
                                           float* __restrict__ Umat) {
    int idx = blockIdx.x * 256 + threadIdx.x;
    int o = idx & 127;
    int d = (idx >> 7) & 127;
    int hh = idx >> 14;
    const float* wv = Wv + ((size_t)hh * HD + d) * HD;
    const float* wc = Wc + (size_t)(hh * HD) * HD + o;
    float s = 0.f;
    for (int m = 0; m < HD; ++m) s += wv[m] * wc[(size_t)m * HD];
    Umat[idx] = s;
}

// ---------------- attention scores ----------------
__global__ __launch_bounds__(256) void k_scores(const float* __restrict__ h2, const float* __restrict__ watt,
                                                float* __restrict__ att) {
    int tid = threadIdx.x;
    int lane = tid & 63;
    int n = blockIdx.x * 4 + (tid >> 6);
    int g = n >> 10;
    float2 x = *(const float2*)(h2 + (size_t)n * HD + lane * 2);
    #pragma unroll
    for (int hh = 0; hh < NHEAD; ++hh) {
        float2 w = *(const float2*)(watt + ((size_t)(hh * NB + g)) * HD + lane * 2);
        float p = x.x * w.x + x.y * w.y;
        p = wsum64(p);
        if (lane == 0) att[(size_t)hh * NN + n] = p;
    }
}

// ---------------- segment softmax ----------------
__global__ __launch_bounds__(256) void k_segsoftmax(const float* __restrict__ att, float* __restrict__ alpha) {
    const int hh = blockIdx.x >> 6, g = blockIdx.x & 63;
    const int t = threadIdx.x;
    const float* a = att + (size_t)hh * NN + g * NPG;
    float* al = alpha + (size_t)hh * NN + g * NPG;
    float v[4]; float mx = -1e30f;
    #pragma unroll
    for (int i = 0; i < 4; ++i) { v[i] = a[t + i * 256]; mx = fmaxf(mx, v[i]); }
    #pragma unroll
    for (int m = 32; m > 0; m >>= 1) mx = fmaxf(mx, __shfl_xor(mx, m, 64));
    __shared__ float redm[4], reds[4];
    if ((t & 63) == 0) redm[t >> 6] = mx;
    __syncthreads();
    mx = fmaxf(fmaxf(redm[0], redm[1]), fmaxf(redm[2], redm[3]));
    float s = 0.f;
    #pragma unroll
    for (int i = 0; i < 4; ++i) { v[i] = __expf(v[i] - mx); s += v[i]; }
    s = wsum64(s);
    if ((t & 63) == 0) reds[t >> 6] = s;
    __syncthreads();
    s = reds[0] + reds[1] + reds[2] + reds[3];
    float inv = 1.f / s;
    #pragma unroll
    for (int i = 0; i < 4; ++i) al[t + i * 256] = v[i] * inv;
}

// ---------------- mo = sum_h alpha_h * (h2 @ U_h) ----------------
__global__ __launch_bounds__(256) void k_mo(const float* __restrict__ h2, const float* __restrict__ Umat,
                                            const float* __restrict__ alpha, float* __restrict__ mo) {
    __shared__ float As[HD * ASTR];
    __shared__ float Ws[BK * HD];
    const int tid = threadIdx.x;
    const int row0 = blockIdx.x * BM;
    const int tr = tid >> 5, tc = tid & 31;
    #pragma unroll
    for (int i = 0; i < 8; ++i) {
        int idx = tid + i * 256;
        int r = idx >> 5, kq = idx & 31;
        float4 v = *(const float4*)(h2 + (size_t)(row0 + r) * HD + kq * 4);
        As[(kq * 4 + 0) * ASTR + r] = v.x;
        As[(kq * 4 + 1) * ASTR + r] = v.y;
        As[(kq * 4 + 2) * ASTR + r] = v.z;
        As[(kq * 4 + 3) * ASTR + r] = v.w;
    }
    float moacc[8][4] = {};
    for (int hh = 0; hh < NHEAD; ++hh) {
        const float* Uh = Umat + (size_t)hh * HD * HD;
        float acc[8][4] = {};
        for (int kc = 0; kc < HD; kc += BK) {
            #pragma unroll
            for (int i = 0; i < 4; ++i) {
                int idx = tid + i * 256;
                int kr = idx >> 5, cq = idx & 31;
                *(float4*)(Ws + kr * HD + cq * 4) = *(const float4*)(Uh + (size_t)(kc + kr) * HD + cq * 4);
            }
            __syncthreads();
            #pragma unroll 4
            for (int k = 0; k < BK; ++k) {
                const float4 a0 = *(const float4*)(As + (kc + k) * ASTR + tr * 8);
                const float4 a1 = *(const float4*)(As + (kc + k) * ASTR + tr * 8 + 4);
                const float4 w  = *(const float4*)(Ws + k * HD + tc * 4);
                float av[8] = {a0.x, a0.y, a0.z, a0.w, a1.x, a1.y, a1.z, a1.w};
                #pragma unroll
                for (int r = 0; r < 8; ++r) {
                    acc[r][0] += av[r] * w.x; acc[r][1] += av[r] * w.y;
                    acc[r][2] += av[r] * w.z; acc[r][3] += av[r] * w.w;
                }
            }
            __syncthreads();
        }
        #pragma unroll
        for (int r = 0; r < 8; ++r) {
            float al = alpha[(size_t)hh * NN + row0 + tr * 8 + r];
            moacc[r][0] += al * acc[r][0]; moacc[r][1] += al * acc[r][1];
            moacc[r][2] += al * acc[r][2]; moacc[r][3] += al * acc[r][3];
        }
    }
    #pragma unroll
    for (int r = 0; r < 8; ++r) {
        int row = row0 + tr * 8 + r;
        *(float4*)(mo + (size_t)row * HD + tc * 4) = make_float4(moacc[r][0], moacc[r][1], moacc[r][2], moacc[r][3]);
    }
}

// ---------------- x1 = LN(mo + h2) ----------------
__global__ __launch_bounds__(256) void k_x1ln(const float* __restrict__ mo, const float* __restrict__ h2,
                                              const float* __restrict__ g, const float* __restrict__ b,
                                              float* __restrict__ x1) {
    int tid = threadIdx.x;
    int lane = tid & 63;
    int n = blockIdx.x * 4 + (tid >> 6);
    float2 m = *(const float2*)(mo + (size_t)n * HD + lane * 2);
    float2 hh = *(const float2*)(h2 + (size_t)n * HD + lane * 2);
    float a0 = m.x + hh.x, a1 = m.y + hh.y;
    float s = a0 + a1, sq = a0 * a0 + a1 * a1;
    #pragma unroll
    for (int mm = 32; mm > 0; mm >>= 1) { s += __shfl_xor(s, mm, 64); sq += __shfl_xor(sq, mm, 64); }
    float mean = s * (1.f / HD);
    float var  = sq * (1.f / HD) - mean * mean;
    float rstd = rsqrtf(var + BEPS);
    float2 gg = *(const float2*)(g + lane * 2);
    float2 bb = *(const float2*)(b + lane * 2);
    float2 o;
    o.x = (a0 - mean) * rstd * gg.x + bb.x;
    o.y = (a1 - mean) * rstd * gg.y + bb.y;
    *(float2*)(x1 + (size_t)n * HD + lane * 2) = o;
}

// ---------------- FFN1: mid = relu(x1 @ Wf1 + bf1), fp16 out ----------------
__global__ __launch_bounds__(256) void k_ffn1(const float* __restrict__ X, const float* __restrict__ W,
                                              const float* __restrict__ bias, __half* __restrict__ midp) {
    __shared__ float As[BK * ASTR];
    __shared__ float Ws[BK * HD];
    const int tid = threadIdx.x;
    const int row0 = (blockIdx.x >> 1) * BM;
    const int c0 = (blockIdx.x & 1) * 128;
    const int tr = tid >> 5, tc = tid & 31;
    float acc[8][4] = {};
    for (int kc = 0; kc < HD; kc += BK) {
        #pragma unroll
        for (int i = 0; i < 2; ++i) {
            int idx = tid * 2 + i;
            int r = idx >> 3, kq = idx & 7;
            float4 v = *(const float4*)(X + (size_t)(row0 + r) * HD + kc + kq * 4);
            As[(kq * 4 + 0) * ASTR + r] = v.x;
            As[(kq * 4 + 1) * ASTR + r] = v.y;
            As[(kq * 4 + 2) * ASTR + r] = v.z;
            As[(kq * 4 + 3) * ASTR + r] = v.w;
        }
        #pragma unroll
        for (int i = 0; i < 4; ++i) {
            int idx = tid + i * 256;
            int kr = idx >> 5, cq = idx & 31;
            *(float4*)(Ws + kr * HD + cq * 4) = *(const float4*)(W + (size_t)(kc + kr) * HD2 + c0 + cq * 4);
        }
        __syncthreads();
        #pragma unroll 4
        for (int k = 0; k < BK; ++k) {
            const float4 a0 = *(const float4*)(As + k * ASTR + tr * 8);
            const float4 a1 = *(const float4*)(As + k * ASTR + tr * 8 + 4);
            const float4 w  = *(const float4*)(Ws + k * HD + tc * 4);
            float av[8] = {a0.x, a0.y, a0.z, a0.w, a1.x, a1.y, a1.z, a1.w};
            #pragma unroll
            for (int r = 0; r < 8; ++r) {
                acc[r][0] += av[r] * w.x; acc[r][1] += av[r] * w.y;
                acc[r][2] += av[r] * w.z; acc[r][3] += av[r] * w.w;
            }
        }
        __syncthreads();
    }
    const float4 bv = *(const float4*)(bias + c0 + tc * 4);
    #pragma unroll
    for (int r = 0; r < 8; ++r) {
        int row = row0 + tr * 8 + r;
        float v0 = fmaxf(acc[r][0] + bv.x, 0.f);
        float v1 = fmaxf(acc[r][1] + bv.y, 0.f);
        float v2 = fmaxf(acc[r][2] + bv.z, 0.f);
        float v3 = fmaxf(acc[r][3] + bv.w, 0.f);
        __half* base = midp + (size_t)row * HD2 + c0 + tc * 4;
        *(__half2*)(base)     = __floats2half2_rn(v0, v1);
        *(__half2*)(base + 2) = __floats2half2_rn(v2, v3);
    }
}

// ---------------- FFN2 + LN + fused graph readout ----------------
__global__ __launch_bounds__(256) void k_ffn2(const __half* __restrict__ midp, const float* __restrict__ W,
                                              const float* __restrict__ bias, const float* __restrict__ x1,
                                              const float* __restrict__ lng, const float* __restrict__ lnb,
                                              float* __restrict__ outp) {
    __shared__ float As[BK * ASTR];
    __shared__ float Ws[BK * HD];
    __shared__ float cred[8 * HD];
    const int tid = threadIdx.x;
    const int row0 = blockIdx.x * BM;
    const int tr = tid >> 5, tc = tid & 31;
    float acc[8][4] = {};
    for (int kc = 0; kc < HD2; kc += BK) {
        {
            int r = tid >> 2, kq = tid & 3;
            union { uint4 u4; __half2 h2v[4]; } uu;
            uu.u4 = *(const uint4*)(midp + (size_t)(row0 + r) * HD2 + kc + kq * 8);
            #pragma unroll
            for (int u = 0; u < 4; ++u) {
                As[(kq * 8 + u * 2 + 0) * ASTR + r] = __low2float(uu.h2v[u]);
                As[(kq * 8 + u * 2 + 1) * ASTR + r] = __high2float(uu.h2v[u]);
            }
        }
        #pragma unroll
        for (int i = 0; i < 4; ++i) {
            int idx = tid + i * 256;
            int kr = idx >> 5, cq = idx & 31;
            *(float4*)(Ws + kr * HD + cq * 4) = *(const float4*)(W + (size_t)(kc + kr) * HD + cq * 4);
        }
        __syncthreads();
        #pragma unroll 4
        for (int k = 0; k < BK; ++k) {
            const float4 a0 = *(const float4*)(As + k * ASTR + tr * 8);
            const float4 a1 = *(const float4*)(As + k * ASTR + tr * 8 + 4);
            const float4 w  = *(const float4*)(Ws + k * HD + tc * 4);
            float av[8] = {a0.x, a0.y, a0.z, a0.w, a1.x, a1.y, a1.z, a1.w};
            #pragma unroll
            for (int r = 0; r < 8; ++r) {
                acc[r][0] += av[r] * w.x; acc[r][1] += av[r] * w.y;
                acc[r][2] += av[r] * w.z; acc[r][3] += av[r] * w.w;
            }
        }
        __syncthreads();
    }
    const float4 bv  = *(const float4*)(bias + tc * 4);
    const float4 gv  = *(const float4*)(lng + tc * 4);
    const float4 bbv = *(const float4*)(lnb + tc * 4);
    float csum0 = 0.f, csum1 = 0.f, csum2 = 0.f, csum3 = 0.f;
    #pragma unroll
    for (int r = 0; r < 8; ++r) {
        int row = row0 + tr * 8 + r;
        const float4 xv = *(const float4*)(x1 + (size_t)row * HD + tc * 4);
        float v0 = acc[r][0] + bv.x + xv.x;
        float v1 = acc[r][1] + bv.y + xv.y;
        float v2 = acc[r][2] + bv.z + xv.z;
        float v3 = acc[r][3] + bv.w + xv.w;
        float s  = v0 + v1 + v2 + v3;
        float sq = v0 * v0 + v1 * v1 + v2 * v2 + v3 * v3;
        #pragma unroll
        for (int m = 1; m <= 16; m <<= 1) {
            s  += __shfl_xor(s, m, 64);
            sq += __shfl_xor(sq, m, 64);
        }
        float mean = s * (1.f / HD);
        float var  = sq * (1.f / HD) - mean * mean;
        float rstd = rsqrtf(var + BEPS);
        v0 = (v0 - mean) * rstd * gv.x + bbv.x;
        v1 = (v1 - mean) * rstd * gv.y + bbv.y;
        v2 = (v2 - mean) * rstd * gv.z + bbv.z;
        v3 = (v3 - mean) * rstd * gv.w + bbv.w;
        csum0 += v0; csum1 += v1; csum2 += v2; csum3 += v3;
    }
    *(float4*)(cred + tr * HD + tc * 4) = make_float4(csum0, csum1, csum2, csum3);
    __syncthreads();
    if (tid < HD) {
        float s = 0.f;
        #pragma unroll
        for (int t = 0; t < 8; ++t) s += cred[t * HD + tid];
        int g = row0 >> 10;
        atomAddF(&outp[g * HD + tid], s);
    }
}

extern "C" void kernel_launch(void* const* d_in, const int* in_sizes, int n_in,
                              void* d_out, int out_size, void* d_ws, size_t ws_size,
                              hipStream_t stream) {
    (void)in_sizes; (void)n_in; (void)out_size;
    const float* h      = (const float*)d_in[0];
    const float* interf = (const float*)d_in[1];
    const float* gamma1 = (const float*)d_in[2];
    const float* beta1  = (const float*)d_in[3];
    const float* W1     = (const float*)d_in[4];
    const float* b1     = (const float*)d_in[5];
    const float* gamma2 = (const float*)d_in[6];
    const float* beta2  = (const float*)d_in[7];
    const float* W2     = (const float*)d_in[8];
    const float* b2     = (const float*)d_in[9];
    const float* Wq     = (const float*)d_in[10];
    const float* Wk     = (const float*)d_in[11];
    const float* Wv     = (const float*)d_in[12];
    const float* Wc     = (const float*)d_in[13];
    const float* ln_g   = (const float*)d_in[14];
    const float* ln_b   = (const float*)d_in[15];
    const float* Wf1    = (const float*)d_in[16];
    const float* bf1    = (const float*)d_in[17];
    const float* Wf2    = (const float*)d_in[18];
    const float* bf2    = (const float*)d_in[19];
    const int*   src    = (const int*)d_in[20];
    const int*   dst    = (const int*)d_in[21];
    // d_in[22] graph_id unused: graphs are contiguous blocks of 1024 nodes

    float* out = (float*)d_out;            // [0:8192) readout, [8192:16384) init_avg_h
    float* P   = (float*)d_ws;             // 32 MB: agg1/agg2 -> mo
    float* Q   = P + 8388608;              // 32 MB: h1 -> (att,alpha) -> x1
    float* Rf  = Q + 8388608;              // 32 MB: h2 -> mid(fp16)
    __half* mid = (__half*)Rf;
    float* att   = Q;                      // overlays h1 region (free after gconv2)
    float* alpha = Q + 262144;
    float* aux  = Rf + 8388608;
    float* dout_r = aux;
    float* din_r  = aux + 65536;
    int*   cnt_o  = (int*)(aux + 131072);
    int*   cnt_i  = (int*)(aux + 196608);
    float* colsum = aux + 262144;
    float* colsq  = colsum + 128;
    float* bscale = colsq + 128;
    float* bshift = bscale + 128;
    float* kvec   = bshift + 128;
    float* watt   = kvec + 32768;
    float* Umat   = watt + 32768;
    int*   offs   = (int*)(Umat + 65536);
    int*   cursor = offs + 65537;
    int*   elist  = cursor + 65536;        // 1M ints

    if (ws_size < (size_t)(8388608 * 3 + 262144 + 512 + 131072 + 65537 + 65536 + 1048576) * 4) return;

    hipMemsetAsync(out, 0, 16384 * 4, stream);
    hipMemsetAsync(cnt_o, 0, 65536 * 4 * 2, stream);
    k_degrees<<<1024, 256, 0, stream>>>(src, dst, cnt_o, cnt_i);
    k_degfin<<<256, 256, 0, stream>>>(cnt_o, cnt_i, dout_r, din_r);
    k_scan<<<1, 1024, 0, stream>>>(cnt_i, offs, cursor);
    k_fill<<<1024, 256, 0, stream>>>(src, dst, cursor, elist);
    k_meanpool<<<512, 128, 0, stream>>>(h, out + 8192);

    // gconv block 1
    hipMemsetAsync(colsum, 0, 256 * 4, stream);
    k_colstats<<<1024, 128, 0, stream>>>(h, colsum, colsq);
    k_bnparams<<<1, 128, 0, stream>>>(colsum, colsq, gamma1, beta1, bscale, bshift);
    k_aggregate<<<16384, 256, 0, stream>>>(h, bscale, bshift, dout_r, din_r, offs, elist, P);
    k_gconv<<<1024, 256, 0, stream>>>(P, W1, b1, h, Q);

    // gconv block 2
    hipMemsetAsync(colsum, 0, 256 * 4, stream);
    k_colstats<<<1024, 128, 0, stream>>>(Q, colsum, colsq);
    k_bnparams<<<1, 128, 0, stream>>>(colsum, colsq, gamma2, beta2, bscale, bshift);
    k_aggregate<<<16384, 256, 0, stream>>>(Q, bscale, bshift, dout_r, din_r, offs, elist, P);
    k_gconv<<<1024, 256, 0, stream>>>(P, W2, b2, Q, Rf);

    // attention (att/alpha overlay the now-dead h1 region in Q)
    k_kvec<<<256, 128, 0, stream>>>(interf, Wk, kvec);
    k_watt<<<256, 128, 0, stream>>>(Wq, kvec, watt);
    k_U<<<256, 256, 0, stream>>>(Wv, Wc, Umat);
    k_scores<<<16384, 256, 0, stream>>>(Rf, watt, att);
    k_segsoftmax<<<256, 256, 0, stream>>>(att, alpha);
    k_mo<<<1024, 256, 0, stream>>>(Rf, Umat, alpha, P);
    k_x1ln<<<16384, 256, 0, stream>>>(P, Rf, ln_g, ln_b, Q);

    // FFN + fused readout
    k_ffn1<<<2048, 256, 0, stream>>>(Q, Wf1, bf1, mid);
    k_ffn2<<<1024, 256, 0, stream>>>(mid, Wf2, bf2, Q, ln_g, ln_b, out);
}

// Round 3
// 589.733 us; speedup vs baseline: 6.9130x; 1.4006x over previous
//
#include <hip/hip_runtime.h>

#define NN 65536
#define NE 1048576
#define NB 64
#define HD 128
#define HD2 256
#define NHEAD 4
#define NPG 1024
#define BEPS 1e-5f
#define BM 64

typedef short bf16x8s __attribute__((ext_vector_type(8)));
typedef float f32x4 __attribute__((ext_vector_type(4)));
#define MFMA16(a,b,c) __builtin_amdgcn_mfma_f32_16x16x32_bf16(a,b,c,0,0,0)

__device__ __forceinline__ unsigned short f2bf(float f) {
    union { float f; unsigned int u; } x{f};
    unsigned int r = x.u + 0x7FFFu + ((x.u >> 16) & 1u);
    return (unsigned short)(r >> 16);
}
__device__ __forceinline__ float b2f(unsigned short s) {
    union { unsigned int u; float f; } x{((unsigned int)s) << 16};
    return x.f;
}
__device__ __forceinline__ void atomAddF(float* p, float v) { unsafeAtomicAdd(p, v); }

// ---------------- degrees ----------------
__global__ __launch_bounds__(256) void k_degrees(const int* __restrict__ src, const int* __restrict__ dst,
                                                 int* __restrict__ cnt_o, int* __restrict__ cnt_i) {
    int i = blockIdx.x * 256 + threadIdx.x;
    #pragma unroll
    for (int j = 0; j < 4; ++j) {
        int e = i + j * (NE / 4);
        atomicAdd(&cnt_o[src[e]], 1);
        atomicAdd(&cnt_i[dst[e]], 1);
    }
}

__global__ __launch_bounds__(256) void k_degfin(const int* __restrict__ cnt_o, const int* __restrict__ cnt_i,
                                                float* __restrict__ dout_r, float* __restrict__ din_r) {
    int n = blockIdx.x * 256 + threadIdx.x;
    dout_r[n] = rsqrtf(fmaxf((float)cnt_o[n], 1.0f));
    din_r[n]  = rsqrtf(fmaxf((float)cnt_i[n], 1.0f));
}

// ---------------- CSR build ----------------
__global__ __launch_bounds__(1024) void k_scan(const int* __restrict__ cnt, int* __restrict__ offs,
                                               int* __restrict__ cursor) {
    __shared__ int sums[1024];
    const int t = threadIdx.x;
    const int base = t * 64;
    int s = 0;
    #pragma unroll 8
    for (int i = 0; i < 64; ++i) s += cnt[base + i];
    sums[t] = s;
    __syncthreads();
    int x = s;
    #pragma unroll
    for (int off = 1; off < 1024; off <<= 1) {
        int v = (t >= off) ? sums[t - off] : 0;
        __syncthreads();
        x += v; sums[t] = x;
        __syncthreads();
    }
    int run = x - s;
    #pragma unroll 8
    for (int i = 0; i < 64; ++i) {
        offs[base + i] = run;
        cursor[base + i] = run;
        run += cnt[base + i];
    }
    if (t == 1023) offs[NN] = run;
}

__global__ __launch_bounds__(256) void k_fill(const int* __restrict__ src, const int* __restrict__ dst,
                                              int* __restrict__ cursor, int* __restrict__ elist) {
    int i = blockIdx.x * 256 + threadIdx.x;
    #pragma unroll
    for (int j = 0; j < 4; ++j) {
        int e = i + j * (NE / 4);
        int pos = atomicAdd(&cursor[dst[e]], 1);
        elist[pos] = src[e];
    }
}

// ---------------- init mean pooling ----------------
__global__ __launch_bounds__(128) void k_meanpool(const float* __restrict__ h, float* __restrict__ out_avg) {
    int g = blockIdx.x >> 3, chunk = blockIdx.x & 7, c = threadIdx.x;
    int r0 = g * NPG + chunk * 128;
    float s = 0.f;
    for (int r = r0; r < r0 + 128; ++r) s += h[(size_t)r * HD + c];
    atomAddF(&out_avg[g * HD + c], s * (1.0f / NPG));
}

// ---------------- BN column stats ----------------
__global__ __launch_bounds__(128) void k_colstats(const float* __restrict__ x,
                                                  float* __restrict__ colsum, float* __restrict__ colsq) {
    int c = threadIdx.x;
    int r0 = blockIdx.x * 64;
    float s = 0.f, sq = 0.f;
    for (int r = r0; r < r0 + 64; ++r) {
        float v = x[(size_t)r * HD + c];
        s += v; sq += v * v;
    }
    atomAddF(&colsum[c], s);
    atomAddF(&colsq[c], sq);
}

__global__ __launch_bounds__(128) void k_bnparams(const float* __restrict__ colsum, const float* __restrict__ colsq,
                                                  const float* __restrict__ g, const float* __restrict__ b,
                                                  float* __restrict__ scale, float* __restrict__ shift) {
    int c = threadIdx.x;
    float mean = colsum[c] * (1.0f / NN);
    float var  = colsq[c] * (1.0f / NN) - mean * mean;
    float rstd = rsqrtf(var + BEPS);
    float sc = rstd * g[c];
    scale[c] = sc;
    shift[c] = b[c] - mean * sc;
}

// ---------------- bnpack: xn[n][c] = bf16((x*sc+sh)*dout_r[n]) ----------------
__global__ __launch_bounds__(256) void k_bnpack(const float* __restrict__ x,
                                                const float* __restrict__ scale, const float* __restrict__ shift,
                                                const float* __restrict__ dout_r, unsigned short* __restrict__ xn) {
    int idx = blockIdx.x * 256 + threadIdx.x;     // N*16 threads, 8 elems each
    int node = idx >> 4;
    int c8 = (idx & 15) * 8;
    float dr = dout_r[node];
    float4 v0 = *(const float4*)(x + (size_t)node * HD + c8);
    float4 v1 = *(const float4*)(x + (size_t)node * HD + c8 + 4);
    float4 sc0 = *(const float4*)(scale + c8), sc1 = *(const float4*)(scale + c8 + 4);
    float4 sh0 = *(const float4*)(shift + c8), sh1 = *(const float4*)(shift + c8 + 4);
    union { uint4 v; unsigned short u[8]; } pk;
    pk.u[0] = f2bf((v0.x * sc0.x + sh0.x) * dr);
    pk.u[1] = f2bf((v0.y * sc0.y + sh0.y) * dr);
    pk.u[2] = f2bf((v0.z * sc0.z + sh0.z) * dr);
    pk.u[3] = f2bf((v0.w * sc0.w + sh0.w) * dr);
    pk.u[4] = f2bf((v1.x * sc1.x + sh1.x) * dr);
    pk.u[5] = f2bf((v1.y * sc1.y + sh1.y) * dr);
    pk.u[6] = f2bf((v1.z * sc1.z + sh1.z) * dr);
    pk.u[7] = f2bf((v1.w * sc1.w + sh1.w) * dr);
    *(uint4*)(xn + (size_t)node * HD + c8) = pk.v;
}

// ---------------- CSR aggregation (bf16 in/out) ----------------
__global__ __launch_bounds__(256) void k_aggregate(const unsigned short* __restrict__ xn,
                                                   const float* __restrict__ din_r,
                                                   const int* __restrict__ offs, const int* __restrict__ elist,
                                                   unsigned short* __restrict__ agg) {
    const int tid = threadIdx.x;
    const int node = blockIdx.x * 4 + (tid >> 6);
    const int lane = tid & 63;
    const int half = lane >> 5;
    const int c4 = (lane & 31) * 4;
    const int beg = offs[node], end = offs[node + 1];
    float a0 = 0.f, a1 = 0.f, a2 = 0.f, a3 = 0.f;
    for (int i = beg + half; i < end; i += 2) {
        int s = elist[i];
        ushort4 v = *(const ushort4*)(xn + (size_t)s * HD + c4);
        a0 += b2f(v.x); a1 += b2f(v.y); a2 += b2f(v.z); a3 += b2f(v.w);
    }
    a0 += __shfl_xor(a0, 32, 64);
    a1 += __shfl_xor(a1, 32, 64);
    a2 += __shfl_xor(a2, 32, 64);
    a3 += __shfl_xor(a3, 32, 64);
    if (half == 0) {
        float dn = din_r[node];
        ushort4 o;
        o.x = f2bf(a0 * dn); o.y = f2bf(a1 * dn); o.z = f2bf(a2 * dn); o.w = f2bf(a3 * dn);
        *(ushort4*)(agg + (size_t)node * HD + c4) = o;
    }
}

// ---------------- weight prep: fragment-linear bf16 ----------------
// frag[((ks*(O/16)+c)*64+l)*8+j] = bf16(W[(ks*32+(l>>4)*8+j)*O + c*16+(l&15)])
__global__ __launch_bounds__(256) void k_prepW(const float* __restrict__ W, unsigned short* __restrict__ frag,
                                               int K, int O) {
    int idx = blockIdx.x * 256 + threadIdx.x;
    int total = (K >> 5) * (O >> 4) * 64;
    if (idx >= total) return;
    int l = idx & 63, t = idx >> 6;
    int ot = O >> 4;
    int c = t % ot, ks = t / ot;
    int q = l >> 4, m = l & 15;
    const float* wp = W + (size_t)(ks * 32 + q * 8) * O + c * 16 + m;
    union { uint4 v; unsigned short u[8]; } pk;
    #pragma unroll
    for (int j = 0; j < 8; ++j) pk.u[j] = f2bf(wp[(size_t)j * O]);
    *(uint4*)(frag + (size_t)idx * 8) = pk.v;
}

// ---------------- attention precomputes ----------------
__global__ __launch_bounds__(128) void k_kvec(const float* __restrict__ interf, const float* __restrict__ Wk,
                                              float* __restrict__ kvec) {
    int hb = blockIdx.x;            // h*64+g
    int hh = hb >> 6, g = hb & 63;
    int o = threadIdx.x;
    __shared__ float f[HD];
    f[o] = interf[g * HD + o];
    __syncthreads();
    const float* Wkh = Wk + (size_t)hh * HD * HD;
    float s = 0.f;
    for (int d = 0; d < HD; ++d) s += f[d] * Wkh[(size_t)d * HD + o];
    kvec[hb * HD + o] = s;
}

__global__ __launch_bounds__(128) void k_watt(const float* __restrict__ Wq, const float* __restrict__ kvec,
                                              float* __restrict__ watt) {
    int hb = blockIdx.x;
    int hh = hb >> 6;
    int d = threadIdx.x;
    __shared__ float kv[HD];
    kv[d] = kvec[hb * HD + d];
    __syncthreads();
    const float* row = Wq + ((size_t)hh * HD + d) * HD;
    float s = 0.f;
    #pragma unroll 4
    for (int o = 0; o < HD; o += 4) {
        float4 w = *(const float4*)(row + o);
        s += w.x * kv[o] + w.y * kv[o + 1] + w.z * kv[o + 2] + w.w * kv[o + 3];
    }
    watt[hb * HD + d] = s * 0.027950849718747373f;   // 1/sqrt(1280)
}

__global__ __launch_bounds__(256) void k_U(const float* __restrict__ Wv, const float* __restrict__ Wc,
                                           float* __restrict__ Umat) {
    int idx = blockIdx.x * 256 + threadIdx.x;
    int o = idx & 127;
    int d = (idx >> 7) & 127;
    int hh = idx >> 14;
    const float* wv = Wv + ((size_t)hh * HD + d) * HD;
    const float* wc = Wc + (size_t)(hh * HD) * HD + o;
    float s = 0.f;
    for (int m = 0; m < HD; ++m) s += wv[m] * wc[(size_t)m * HD];
    Umat[idx] = s;
}

// ---------------- gconv MFMA: out = res + relu(agg @ W + b); optional fused scores ----------------
template<bool SCORES>
__global__ __launch_bounds__(256) void k_gconv_mfma(const unsigned short* __restrict__ agg,
                                                    const unsigned short* __restrict__ Wfrag,
                                                    const float* __restrict__ bias,
                                                    const float* __restrict__ res, float* __restrict__ outp,
                                                    const float* __restrict__ watt, float* __restrict__ att) {
    const int tid = threadIdx.x;
    const int w = tid >> 6, l = tid & 63, q = l >> 4, m = l & 15;
    const int node = blockIdx.x * BM + w * 16 + m;
    bf16x8s a[4];
    #pragma unroll
    for (int ks = 0; ks < 4; ++ks)
        a[ks] = *(const bf16x8s*)(agg + (size_t)node * HD + ks * 32 + q * 8);
    f32x4 acc[8] = {};
    #pragma unroll
    for (int ks = 0; ks < 4; ++ks) {
        #pragma unroll
        for (int c = 0; c < 8; ++c) {
            bf16x8s b = *(const bf16x8s*)(Wfrag + (size_t)((ks * 8 + c) * 64 + l) * 8);
            acc[c] = MFMA16(b, a[ks], acc[c]);
        }
    }
    float vals[8][4];
    #pragma unroll
    for (int c = 0; c < 8; ++c) {
        const int col = c * 16 + q * 4;
        float4 bv = *(const float4*)(bias + col);
        float4 rv = *(const float4*)(res + (size_t)node * HD + col);
        vals[c][0] = rv.x + fmaxf(acc[c][0] + bv.x, 0.f);
        vals[c][1] = rv.y + fmaxf(acc[c][1] + bv.y, 0.f);
        vals[c][2] = rv.z + fmaxf(acc[c][2] + bv.z, 0.f);
        vals[c][3] = rv.w + fmaxf(acc[c][3] + bv.w, 0.f);
        *(float4*)(outp + (size_t)node * HD + col) = make_float4(vals[c][0], vals[c][1], vals[c][2], vals[c][3]);
    }
    if (SCORES) {
        const int g = node >> 10;
        #pragma unroll
        for (int hh = 0; hh < NHEAD; ++hh) {
            const float* wp = watt + ((size_t)(hh * NB + g)) * HD;
            float s = 0.f;
            #pragma unroll
            for (int c = 0; c < 8; ++c) {
                const int col = c * 16 + q * 4;
                float4 wv = *(const float4*)(wp + col);
                s += vals[c][0] * wv.x + vals[c][1] * wv.y + vals[c][2] * wv.z + vals[c][3] * wv.w;
            }
            s += __shfl_xor(s, 16, 64);
            s += __shfl_xor(s, 32, 64);
            if (q == 0) att[(size_t)hh * NN + node] = s;
        }
    }
}

// ---------------- segment softmax ----------------
__global__ __launch_bounds__(256) void k_segsoftmax(const float* __restrict__ att, float* __restrict__ alpha) {
    const int hh = blockIdx.x >> 6, g = blockIdx.x & 63;
    const int t = threadIdx.x;
    const float* a = att + (size_t)hh * NN + g * NPG;
    float* al = alpha + (size_t)hh * NN + g * NPG;
    float v[4]; float mx = -1e30f;
    #pragma unroll
    for (int i = 0; i < 4; ++i) { v[i] = a[t + i * 256]; mx = fmaxf(mx, v[i]); }
    #pragma unroll
    for (int m = 32; m > 0; m >>= 1) mx = fmaxf(mx, __shfl_xor(mx, m, 64));
    __shared__ float redm[4], reds[4];
    if ((t & 63) == 0) redm[t >> 6] = mx;
    __syncthreads();
    mx = fmaxf(fmaxf(redm[0], redm[1]), fmaxf(redm[2], redm[3]));
    float s = 0.f;
    #pragma unroll
    for (int i = 0; i < 4; ++i) { v[i] = __expf(v[i] - mx); s += v[i]; }
    #pragma unroll
    for (int m = 32; m > 0; m >>= 1) s += __shfl_xor(s, m, 64);
    if ((t & 63) == 0) reds[t >> 6] = s;
    __syncthreads();
    s = reds[0] + reds[1] + reds[2] + reds[3];
    float inv = 1.f / s;
    #pragma unroll
    for (int i = 0; i < 4; ++i) al[t + i * 256] = v[i] * inv;
}

// ---------------- mo + x1 = LN(mo + h2) fused ----------------
__global__ __launch_bounds__(256) void k_mo_x1(const float* __restrict__ h2,
                                               const unsigned short* __restrict__ Ufrag,
                                               const float* __restrict__ alpha,
                                               const float* __restrict__ lng, const float* __restrict__ lnb,
                                               float* __restrict__ x1) {
    const int tid = threadIdx.x;
    const int w = tid >> 6, l = tid & 63, q = l >> 4, m = l & 15;
    const int node = blockIdx.x * BM + w * 16 + m;
    bf16x8s a[4];
    #pragma unroll
    for (int ks = 0; ks < 4; ++ks) {
        float4 v0 = *(const float4*)(h2 + (size_t)node * HD + ks * 32 + q * 8);
        float4 v1 = *(const float4*)(h2 + (size_t)node * HD + ks * 32 + q * 8 + 4);
        union { bf16x8s v; unsigned short u[8]; } pk;
        pk.u[0] = f2bf(v0.x); pk.u[1] = f2bf(v0.y); pk.u[2] = f2bf(v0.z); pk.u[3] = f2bf(v0.w);
        pk.u[4] = f2bf(v1.x); pk.u[5] = f2bf(v1.y); pk.u[6] = f2bf(v1.z); pk.u[7] = f2bf(v1.w);
        a[ks] = pk.v;
    }
    f32x4 mo[8] = {};
    #pragma unroll
    for (int hh = 0; hh < 4; ++hh) {
        f32x4 acc[8] = {};
        #pragma unroll
        for (int ks = 0; ks < 4; ++ks) {
            #pragma unroll
            for (int c = 0; c < 8; ++c) {
                bf16x8s b = *(const bf16x8s*)(Ufrag + (size_t)(((hh * 4 + ks) * 8 + c) * 64 + l) * 8);
                acc[c] = MFMA16(b, a[ks], acc[c]);
            }
        }
        float al = alpha[(size_t)hh * NN + node];
        #pragma unroll
        for (int c = 0; c < 8; ++c) {
            mo[c][0] += al * acc[c][0];
            mo[c][1] += al * acc[c][1];
            mo[c][2] += al * acc[c][2];
            mo[c][3] += al * acc[c][3];
        }
    }
    float vals[8][4]; float s = 0.f, sq = 0.f;
    #pragma unroll
    for (int c = 0; c < 8; ++c) {
        const int col = c * 16 + q * 4;
        float4 hv = *(const float4*)(h2 + (size_t)node * HD + col);
        vals[c][0] = mo[c][0] + hv.x;
        vals[c][1] = mo[c][1] + hv.y;
        vals[c][2] = mo[c][2] + hv.z;
        vals[c][3] = mo[c][3] + hv.w;
        #pragma unroll
        for (int r = 0; r < 4; ++r) { s += vals[c][r]; sq += vals[c][r] * vals[c][r]; }
    }
    s  += __shfl_xor(s, 16, 64);  s  += __shfl_xor(s, 32, 64);
    sq += __shfl_xor(sq, 16, 64); sq += __shfl_xor(sq, 32, 64);
    float mean = s * (1.f / HD);
    float var  = sq * (1.f / HD) - mean * mean;
    float rstd = rsqrtf(var + BEPS);
    #pragma unroll
    for (int c = 0; c < 8; ++c) {
        const int col = c * 16 + q * 4;
        float4 gv = *(const float4*)(lng + col);
        float4 bv = *(const float4*)(lnb + col);
        float4 o;
        o.x = (vals[c][0] - mean) * rstd * gv.x + bv.x;
        o.y = (vals[c][1] - mean) * rstd * gv.y + bv.y;
        o.z = (vals[c][2] - mean) * rstd * gv.z + bv.z;
        o.w = (vals[c][3] - mean) * rstd * gv.w + bv.w;
        *(float4*)(x1 + (size_t)node * HD + col) = o;
    }
}

// ---------------- FFN1: mid = bf16(relu(x1 @ Wf1 + bf1)) ----------------
__global__ __launch_bounds__(256) void k_ffn1_mfma(const float* __restrict__ X,
                                                   const unsigned short* __restrict__ Wfrag,
                                                   const float* __restrict__ bias,
                                                   unsigned short* __restrict__ mid) {
    const int tid = threadIdx.x;
    const int w = tid >> 6, l = tid & 63, q = l >> 4, m = l & 15;
    const int node = blockIdx.x * BM + w * 16 + m;
    bf16x8s a[4];
    #pragma unroll
    for (int ks = 0; ks < 4; ++ks) {
        float4 v0 = *(const float4*)(X + (size_t)node * HD + ks * 32 + q * 8);
        float4 v1 = *(const float4*)(X + (size_t)node * HD + ks * 32 + q * 8 + 4);
        union { bf16x8s v; unsigned short u[8]; } pk;
        pk.u[0] = f2bf(v0.x); pk.u[1] = f2bf(v0.y); pk.u[2] = f2bf(v0.z); pk.u[3] = f2bf(v0.w);
        pk.u[4] = f2bf(v1.x); pk.u[5] = f2bf(v1.y); pk.u[6] = f2bf(v1.z); pk.u[7] = f2bf(v1.w);
        a[ks] = pk.v;
    }
    f32x4 acc[16] = {};
    #pragma unroll
    for (int ks = 0; ks < 4; ++ks) {
        #pragma unroll
        for (int c = 0; c < 16; ++c) {
            bf16x8s b = *(const bf16x8s*)(Wfrag + (size_t)((ks * 16 + c) * 64 + l) * 8);
            acc[c] = MFMA16(b, a[ks], acc[c]);
        }
    }
    #pragma unroll
    for (int c = 0; c < 16; ++c) {
        const int col = c * 16 + q * 4;
        float4 bv = *(const float4*)(bias + col);
        ushort4 o;
        o.x = f2bf(fmaxf(acc[c][0] + bv.x, 0.f));
        o.y = f2bf(fmaxf(acc[c][1] + bv.y, 0.f));
        o.z = f2bf(fmaxf(acc[c][2] + bv.z, 0.f));
        o.w = f2bf(fmaxf(acc[c][3] + bv.w, 0.f));
        *(ushort4*)(mid + (size_t)node * HD2 + col) = o;
    }
}

// ---------------- FFN2 + LN + fused graph readout ----------------
__global__ __launch_bounds__(256) void k_ffn2_mfma(const unsigned short* __restrict__ mid,
                                                   const unsigned short* __restrict__ Wfrag,
                                                   const float* __restrict__ bias,
                                                   const float* __restrict__ x1,
                                                   const float* __restrict__ lng, const float* __restrict__ lnb,
                                                   float* __restrict__ outp) {
    __shared__ float cred[4 * HD];
    const int tid = threadIdx.x;
    const int w = tid >> 6, l = tid & 63, q = l >> 4, m = l & 15;
    const int node = blockIdx.x * BM + w * 16 + m;
    bf16x8s a[8];
    #pragma unroll
    for (int ks = 0; ks < 8; ++ks)
        a[ks] = *(const bf16x8s*)(mid + (size_t)node * HD2 + ks * 32 + q * 8);
    f32x4 acc[8] = {};
    #pragma unroll
    for (int ks = 0; ks < 8; ++ks) {
        #pragma unroll
        for (int c = 0; c < 8; ++c) {
            bf16x8s b = *(const bf16x8s*)(Wfrag + (size_t)((ks * 8 + c) * 64 + l) * 8);
            acc[c] = MFMA16(b, a[ks], acc[c]);
        }
    }
    float vals[8][4]; float s = 0.f, sq = 0.f;
    #pragma unroll
    for (int c = 0; c < 8; ++c) {
        const int col = c * 16 + q * 4;
        float4 bv = *(const float4*)(bias + col);
        float4 xv = *(const float4*)(x1 + (size_t)node * HD + col);
        vals[c][0] = acc[c][0] + bv.x + xv.x;
        vals[c][1] = acc[c][1] + bv.y + xv.y;
        vals[c][2] = acc[c][2] + bv.z + xv.z;
        vals[c][3] = acc[c][3] + bv.w + xv.w;
        #pragma unroll
        for (int r = 0; r < 4; ++r) { s += vals[c][r]; sq += vals[c][r] * vals[c][r]; }
    }
    s  += __shfl_xor(s, 16, 64);  s  += __shfl_xor(s, 32, 64);
    sq += __shfl_xor(sq, 16, 64); sq += __shfl_xor(sq, 32, 64);
    float mean = s * (1.f / HD);
    float var  = sq * (1.f / HD) - mean * mean;
    float rstd = rsqrtf(var + BEPS);
    #pragma unroll
    for (int c = 0; c < 8; ++c) {
        const int col = c * 16 + q * 4;
        float4 gv = *(const float4*)(lng + col);
        float4 bv = *(const float4*)(lnb + col);
        float4 o;
        o.x = (vals[c][0] - mean) * rstd * gv.x + bv.x;
        o.y = (vals[c][1] - mean) * rstd * gv.y + bv.y;
        o.z = (vals[c][2] - mean) * rstd * gv.z + bv.z;
        o.w = (vals[c][3] - mean) * rstd * gv.w + bv.w;
        #pragma unroll
        for (int mk = 1; mk <= 8; mk <<= 1) {
            o.x += __shfl_xor(o.x, mk, 64);
            o.y += __shfl_xor(o.y, mk, 64);
            o.z += __shfl_xor(o.z, mk, 64);
            o.w += __shfl_xor(o.w, mk, 64);
        }
        if (m == 0) *(float4*)(cred + w * HD + col) = o;
    }
    __syncthreads();
    if (tid < HD) {
        float sum = cred[tid] + cred[HD + tid] + cred[2 * HD + tid] + cred[3 * HD + tid];
        int g = blockIdx.x >> 4;   // 64 rows/block, 1024/graph
        atomAddF(&outp[g * HD + tid], sum);
    }
}

extern "C" void kernel_launch(void* const* d_in, const int* in_sizes, int n_in,
                              void* d_out, int out_size, void* d_ws, size_t ws_size,
                              hipStream_t stream) {
    (void)in_sizes; (void)n_in; (void)out_size;
    const float* h      = (const float*)d_in[0];
    const float* interf = (const float*)d_in[1];
    const float* gamma1 = (const float*)d_in[2];
    const float* beta1  = (const float*)d_in[3];
    const float* W1     = (const float*)d_in[4];
    const float* b1     = (const float*)d_in[5];
    const float* gamma2 = (const float*)d_in[6];
    const float* beta2  = (const float*)d_in[7];
    const float* W2     = (const float*)d_in[8];
    const float* b2     = (const float*)d_in[9];
    const float* Wq     = (const float*)d_in[10];
    const float* Wk     = (const float*)d_in[11];
    const float* Wv     = (const float*)d_in[12];
    const float* Wc     = (const float*)d_in[13];
    const float* ln_g   = (const float*)d_in[14];
    const float* ln_b   = (const float*)d_in[15];
    const float* Wf1    = (const float*)d_in[16];
    const float* bf1    = (const float*)d_in[17];
    const float* Wf2    = (const float*)d_in[18];
    const float* bf2    = (const float*)d_in[19];
    const int*   src    = (const int*)d_in[20];
    const int*   dst    = (const int*)d_in[21];

    float* out = (float*)d_out;              // [0:8192) readout, [8192:16384) init_avg_h
    float* R1 = (float*)d_ws;                // 32MB: (cnt scratch) -> h1 -> x1
    float* R2 = R1 + 8388608;                // 32MB: h2 -> mid(bf16)
    float* R3 = R2 + 8388608;                // 32MB: xn bf16 | agg bf16 ; att/alpha overlay xn later
    float* aux = R3 + 8388608;

    float* h1 = R1;
    float* x1 = R1;
    float* h2 = R2;
    unsigned short* mid  = (unsigned short*)R2;
    unsigned short* xn   = (unsigned short*)R3;                 // 16MB
    unsigned short* aggb = (unsigned short*)(R3 + 4194304);     // 16MB
    float* att   = R3;                       // overlays xn (dead by then)
    float* alpha = R3 + 262144;
    int* cnt_o = (int*)R1;                   // early scratch, dead before h1 written
    int* cnt_i = cnt_o + 65536;

    float* dout_r = aux;
    float* din_r  = aux + 65536;
    float* colsum = aux + 131072;
    float* colsq  = colsum + 128;
    float* bscale = colsq + 128;
    float* bshift = bscale + 128;
    float* kvec   = aux + 131584;
    float* watt   = aux + 164352;
    float* Umat   = aux + 197120;
    int*   offs   = (int*)(aux + 262656);
    int*   cursor = offs + 65537;
    int*   elist  = cursor + 65536;          // 1M ints, ends at 1442305
    unsigned short* W1f  = (unsigned short*)(aux + 1442308);   // 16B-aligned
    unsigned short* W2f  = W1f + 16384;
    unsigned short* Wf1f = W2f + 16384;      // 32768
    unsigned short* Wf2f = Wf1f + 32768;     // 32768
    unsigned short* Uf   = Wf2f + 32768;     // 65536

    if (ws_size < (size_t)106760208u) return;

    hipMemsetAsync(out, 0, 16384 * 4, stream);
    hipMemsetAsync(cnt_o, 0, 65536 * 4 * 2, stream);
    k_degrees<<<1024, 256, 0, stream>>>(src, dst, cnt_o, cnt_i);
    k_degfin<<<256, 256, 0, stream>>>(cnt_o, cnt_i, dout_r, din_r);
    k_scan<<<1, 1024, 0, stream>>>(cnt_i, offs, cursor);
    k_fill<<<1024, 256, 0, stream>>>(src, dst, cursor, elist);
    k_meanpool<<<512, 128, 0, stream>>>(h, out + 8192);

    // weight prep (all L2-resident, tiny)
    k_prepW<<<8, 256, 0, stream>>>(W1, W1f, 128, 128);
    k_prepW<<<8, 256, 0, stream>>>(W2, W2f, 128, 128);
    k_prepW<<<16, 256, 0, stream>>>(Wf1, Wf1f, 128, 256);
    k_prepW<<<16, 256, 0, stream>>>(Wf2, Wf2f, 256, 128);
    k_kvec<<<256, 128, 0, stream>>>(interf, Wk, kvec);
    k_watt<<<256, 128, 0, stream>>>(Wq, kvec, watt);
    k_U<<<256, 256, 0, stream>>>(Wv, Wc, Umat);
    for (int hh = 0; hh < 4; ++hh)
        k_prepW<<<8, 256, 0, stream>>>(Umat + hh * 16384, Uf + hh * 16384, 128, 128);

    // gconv block 1
    hipMemsetAsync(colsum, 0, 256 * 4, stream);
    k_colstats<<<1024, 128, 0, stream>>>(h, colsum, colsq);
    k_bnparams<<<1, 128, 0, stream>>>(colsum, colsq, gamma1, beta1, bscale, bshift);
    k_bnpack<<<4096, 256, 0, stream>>>(h, bscale, bshift, dout_r, xn);
    k_aggregate<<<16384, 256, 0, stream>>>(xn, din_r, offs, elist, aggb);
    k_gconv_mfma<false><<<1024, 256, 0, stream>>>(aggb, W1f, b1, h, h1, nullptr, nullptr);

    // gconv block 2 (+ fused attention scores)
    hipMemsetAsync(colsum, 0, 256 * 4, stream);
    k_colstats<<<1024, 128, 0, stream>>>(h1, colsum, colsq);
    k_bnparams<<<1, 128, 0, stream>>>(colsum, colsq, gamma2, beta2, bscale, bshift);
    k_bnpack<<<4096, 256, 0, stream>>>(h1, bscale, bshift, dout_r, xn);
    k_aggregate<<<16384, 256, 0, stream>>>(xn, din_r, offs, elist, aggb);
    k_gconv_mfma<true><<<1024, 256, 0, stream>>>(aggb, W2f, b2, h1, h2, watt, att);

    // attention softmax + mo + x1
    k_segsoftmax<<<256, 256, 0, stream>>>(att, alpha);
    k_mo_x1<<<1024, 256, 0, stream>>>(h2, Uf, alpha, ln_g, ln_b, x1);

    // FFN + fused readout
    k_ffn1_mfma<<<1024, 256, 0, stream>>>(x1, Wf1f, bf1, mid);
    k_ffn2_mfma<<<1024, 256, 0, stream>>>(mid, Wf2f, bf2, x1, ln_g, ln_b, out);
}

// Round 4
// 466.362 us; speedup vs baseline: 8.7417x; 1.2645x over previous
//
#include <hip/hip_runtime.h>

#define NN 65536
#define NE 1048576
#define NB 64
#define HD 128
#define HD2 256
#define NHEAD 4
#define NPG 1024
#define BEPS 1e-5f
#define BM 64

typedef short bf16x8s __attribute__((ext_vector_type(8)));
typedef float f32x4 __attribute__((ext_vector_type(4)));
#define MFMA16(a,b,c) __builtin_amdgcn_mfma_f32_16x16x32_bf16(a,b,c,0,0,0)

__device__ __forceinline__ unsigned short f2bf(float f) {
    union { float f; unsigned int u; } x{f};
    unsigned int r = x.u + 0x7FFFu + ((x.u >> 16) & 1u);
    return (unsigned short)(r >> 16);
}
__device__ __forceinline__ float b2f(unsigned short s) {
    union { unsigned int u; float f; } x{((unsigned int)s) << 16};
    return x.f;
}
__device__ __forceinline__ void atomAddF(float* p, float v) { unsafeAtomicAdd(p, v); }

// ---------------- graph prep pass 1: degrees + per-edge rank ----------------
__global__ __launch_bounds__(256) void k_prep1(const int* __restrict__ src, const int* __restrict__ dst,
                                               int* __restrict__ cnt_o, int* __restrict__ cnt_i,
                                               unsigned short* __restrict__ rank) {
    int i = blockIdx.x * 256 + threadIdx.x;
    #pragma unroll
    for (int j = 0; j < 4; ++j) {
        int e = i + j * (NE / 4);
        atomicAdd(&cnt_o[src[e]], 1);
        int r = atomicAdd(&cnt_i[dst[e]], 1);
        rank[e] = (unsigned short)r;
    }
}

__global__ __launch_bounds__(256) void k_degfin(const int* __restrict__ cnt_o, const int* __restrict__ cnt_i,
                                                float* __restrict__ dout_r, float* __restrict__ din_r) {
    int n = blockIdx.x * 256 + threadIdx.x;
    dout_r[n] = rsqrtf(fmaxf((float)cnt_o[n], 1.0f));
    din_r[n]  = rsqrtf(fmaxf((float)cnt_i[n], 1.0f));
}

__global__ __launch_bounds__(1024) void k_scan(const int* __restrict__ cnt, int* __restrict__ offs) {
    __shared__ int sums[1024];
    const int t = threadIdx.x;
    const int base = t * 64;
    int s = 0;
    #pragma unroll 8
    for (int i = 0; i < 64; ++i) s += cnt[base + i];
    sums[t] = s;
    __syncthreads();
    int x = s;
    #pragma unroll
    for (int off = 1; off < 1024; off <<= 1) {
        int v = (t >= off) ? sums[t - off] : 0;
        __syncthreads();
        x += v; sums[t] = x;
        __syncthreads();
    }
    int run = x - s;
    #pragma unroll 8
    for (int i = 0; i < 64; ++i) {
        offs[base + i] = run;
        run += cnt[base + i];
    }
    if (t == 1023) offs[NN] = run;
}

// ---------------- graph prep pass 2: atomic-free CSR fill ----------------
__global__ __launch_bounds__(256) void k_fill2(const int* __restrict__ src, const int* __restrict__ dst,
                                               const int* __restrict__ offs, const unsigned short* __restrict__ rank,
                                               int* __restrict__ elist) {
    int i = blockIdx.x * 256 + threadIdx.x;
    #pragma unroll
    for (int j = 0; j < 4; ++j) {
        int e = i + j * (NE / 4);
        elist[offs[dst[e]] + (int)rank[e]] = src[e];
    }
}

// ---------------- mean pooling + BN column stats of h (one pass) ----------------
__global__ __launch_bounds__(128) void k_pool_colstats(const float* __restrict__ h, float* __restrict__ out_avg,
                                                       float* __restrict__ colsum, float* __restrict__ colsq) {
    int c = threadIdx.x;
    int r0 = blockIdx.x * 64;            // grid 1024; 64 rows, all inside graph r0>>10
    float s = 0.f, sq = 0.f;
    for (int r = r0; r < r0 + 64; ++r) {
        float v = h[(size_t)r * HD + c];
        s += v; sq += v * v;
    }
    int g = r0 >> 10;
    atomAddF(&out_avg[g * HD + c], s * (1.0f / NPG));
    atomAddF(&colsum[c], s);
    atomAddF(&colsq[c], sq);
}

// ---------------- bnpack (inline BN params): xn = bf16((x*sc+sh)*dout_r) ----------------
__global__ __launch_bounds__(256) void k_bnpack(const float* __restrict__ x,
                                                const float* __restrict__ colsum, const float* __restrict__ colsq,
                                                const float* __restrict__ gma, const float* __restrict__ bta,
                                                const float* __restrict__ dout_r, unsigned short* __restrict__ xn) {
    int idx = blockIdx.x * 256 + threadIdx.x;     // N*16 threads, 8 elems each
    int node = idx >> 4;
    int c8 = (idx & 15) * 8;
    float sc[8], sh[8];
    #pragma unroll
    for (int j = 0; j < 8; ++j) {
        float mean = colsum[c8 + j] * (1.0f / NN);
        float var  = colsq[c8 + j] * (1.0f / NN) - mean * mean;
        float rstd = rsqrtf(var + BEPS);
        sc[j] = rstd * gma[c8 + j];
        sh[j] = bta[c8 + j] - mean * sc[j];
    }
    float dr = dout_r[node];
    float4 v0 = *(const float4*)(x + (size_t)node * HD + c8);
    float4 v1 = *(const float4*)(x + (size_t)node * HD + c8 + 4);
    union { uint4 v; unsigned short u[8]; } pk;
    pk.u[0] = f2bf((v0.x * sc[0] + sh[0]) * dr);
    pk.u[1] = f2bf((v0.y * sc[1] + sh[1]) * dr);
    pk.u[2] = f2bf((v0.z * sc[2] + sh[2]) * dr);
    pk.u[3] = f2bf((v0.w * sc[3] + sh[3]) * dr);
    pk.u[4] = f2bf((v1.x * sc[4] + sh[4]) * dr);
    pk.u[5] = f2bf((v1.y * sc[5] + sh[5]) * dr);
    pk.u[6] = f2bf((v1.z * sc[6] + sh[6]) * dr);
    pk.u[7] = f2bf((v1.w * sc[7] + sh[7]) * dr);
    *(uint4*)(xn + (size_t)node * HD + c8) = pk.v;
}

// ---------------- CSR aggregation: wave per node, 4-edge ILP ----------------
__global__ __launch_bounds__(256) void k_aggregate(const unsigned short* __restrict__ xn,
                                                   const float* __restrict__ din_r,
                                                   const int* __restrict__ offs, const int* __restrict__ elist,
                                                   unsigned short* __restrict__ agg) {
    const int tid = threadIdx.x;
    const int node = blockIdx.x * 4 + (tid >> 6);
    const int c2 = (tid & 63) * 2;
    const int beg = offs[node], end = offs[node + 1];
    float a0 = 0.f, a1 = 0.f;
    int i = beg;
    for (; i + 4 <= end; i += 4) {
        int s0 = elist[i], s1 = elist[i + 1], s2 = elist[i + 2], s3 = elist[i + 3];
        unsigned int v0 = *(const unsigned int*)(xn + (size_t)s0 * HD + c2);
        unsigned int v1 = *(const unsigned int*)(xn + (size_t)s1 * HD + c2);
        unsigned int v2 = *(const unsigned int*)(xn + (size_t)s2 * HD + c2);
        unsigned int v3 = *(const unsigned int*)(xn + (size_t)s3 * HD + c2);
        a0 += b2f((unsigned short)v0) + b2f((unsigned short)v1) + b2f((unsigned short)v2) + b2f((unsigned short)v3);
        a1 += b2f((unsigned short)(v0 >> 16)) + b2f((unsigned short)(v1 >> 16))
            + b2f((unsigned short)(v2 >> 16)) + b2f((unsigned short)(v3 >> 16));
    }
    for (; i < end; ++i) {
        int s = elist[i];
        unsigned int v = *(const unsigned int*)(xn + (size_t)s * HD + c2);
        a0 += b2f((unsigned short)v);
        a1 += b2f((unsigned short)(v >> 16));
    }
    float dn = din_r[node];
    ushort2 o;
    o.x = f2bf(a0 * dn); o.y = f2bf(a1 * dn);
    *(ushort2*)(agg + (size_t)node * HD + c2) = o;
}

// ---------------- weight prep: fragment-linear bf16 ----------------
__global__ __launch_bounds__(256) void k_prepW(const float* __restrict__ W, unsigned short* __restrict__ frag,
                                               int K, int O) {
    int idx = blockIdx.x * 256 + threadIdx.x;
    int total = (K >> 5) * (O >> 4) * 64;
    if (idx >= total) return;
    int l = idx & 63, t = idx >> 6;
    int ot = O >> 4;
    int c = t % ot, ks = t / ot;
    int q = l >> 4, m = l & 15;
    const float* wp = W + (size_t)(ks * 32 + q * 8) * O + c * 16 + m;
    union { uint4 v; unsigned short u[8]; } pk;
    #pragma unroll
    for (int j = 0; j < 8; ++j) pk.u[j] = f2bf(wp[(size_t)j * O]);
    *(uint4*)(frag + (size_t)idx * 8) = pk.v;
}

// ---------------- attention score-weight precompute (kvec+watt fused) ----------------
__global__ __launch_bounds__(128) void k_kw(const float* __restrict__ interf, const float* __restrict__ Wk,
                                            const float* __restrict__ Wq, float* __restrict__ watt) {
    int hb = blockIdx.x;            // h*64+g
    int hh = hb >> 6, g = hb & 63;
    int t = threadIdx.x;
    __shared__ float f[HD];
    __shared__ float kv[HD];
    f[t] = interf[g * HD + t];
    __syncthreads();
    const float* Wkh = Wk + (size_t)hh * HD * HD;
    float s = 0.f;
    for (int d = 0; d < HD; ++d) s += f[d] * Wkh[(size_t)d * HD + t];
    kv[t] = s;
    __syncthreads();
    const float* row = Wq + ((size_t)hh * HD + t) * HD;
    float s2 = 0.f;
    #pragma unroll 4
    for (int o = 0; o < HD; o += 4) {
        float4 w = *(const float4*)(row + o);
        s2 += w.x * kv[o] + w.y * kv[o + 1] + w.z * kv[o + 2] + w.w * kv[o + 3];
    }
    watt[hb * HD + t] = s2 * 0.027950849718747373f;   // 1/sqrt(1280)
}

// ---------------- U = Wv@Wc_h, written directly in fragment layout ----------------
__global__ __launch_bounds__(256) void k_Ufrag(const float* __restrict__ Wv, const float* __restrict__ Wc,
                                               unsigned short* __restrict__ Uf) {
    int idx = blockIdx.x * 256 + threadIdx.x;   // 65536
    int o = idx & 127;
    int d = (idx >> 7) & 127;
    int hh = idx >> 14;
    const float* wv = Wv + ((size_t)hh * HD + d) * HD;
    const float* wc = Wc + (size_t)(hh * HD) * HD + o;
    float s = 0.f;
    for (int m2 = 0; m2 < HD; ++m2) s += wv[m2] * wc[(size_t)m2 * HD];
    int ks = d >> 5, dd = d & 31, q = dd >> 3, j = dd & 7;
    int c = o >> 4, m = o & 15, l = q * 16 + m;
    Uf[(size_t)((((hh * 4 + ks) * 8 + c) * 64 + l) * 8 + j)] = f2bf(s);
}

// ---------------- gconv MFMA: out = res + relu(agg @ W + b); fused scores / colstats ----------------
template<bool SCORES, bool STATS>
__global__ __launch_bounds__(256) void k_gconv_mfma(const unsigned short* __restrict__ agg,
                                                    const unsigned short* __restrict__ Wfrag,
                                                    const float* __restrict__ bias,
                                                    const float* __restrict__ res, float* __restrict__ outp,
                                                    const float* __restrict__ watt, float* __restrict__ att,
                                                    float* __restrict__ colsum, float* __restrict__ colsq) {
    __shared__ float credS[4 * HD];
    __shared__ float credQ[4 * HD];
    const int tid = threadIdx.x;
    const int w = tid >> 6, l = tid & 63, q = l >> 4, m = l & 15;
    const int node = blockIdx.x * BM + w * 16 + m;
    bf16x8s a[4];
    #pragma unroll
    for (int ks = 0; ks < 4; ++ks)
        a[ks] = *(const bf16x8s*)(agg + (size_t)node * HD + ks * 32 + q * 8);
    f32x4 acc[8] = {};
    #pragma unroll
    for (int ks = 0; ks < 4; ++ks) {
        #pragma unroll
        for (int c = 0; c < 8; ++c) {
            bf16x8s b = *(const bf16x8s*)(Wfrag + (size_t)((ks * 8 + c) * 64 + l) * 8);
            acc[c] = MFMA16(b, a[ks], acc[c]);
        }
    }
    float vals[8][4];
    #pragma unroll
    for (int c = 0; c < 8; ++c) {
        const int col = c * 16 + q * 4;
        float4 bv = *(const float4*)(bias + col);
        float4 rv = *(const float4*)(res + (size_t)node * HD + col);
        vals[c][0] = rv.x + fmaxf(acc[c][0] + bv.x, 0.f);
        vals[c][1] = rv.y + fmaxf(acc[c][1] + bv.y, 0.f);
        vals[c][2] = rv.z + fmaxf(acc[c][2] + bv.z, 0.f);
        vals[c][3] = rv.w + fmaxf(acc[c][3] + bv.w, 0.f);
        *(float4*)(outp + (size_t)node * HD + col) = make_float4(vals[c][0], vals[c][1], vals[c][2], vals[c][3]);
    }
    if (SCORES) {
        const int g = node >> 10;
        #pragma unroll
        for (int hh = 0; hh < NHEAD; ++hh) {
            const float* wp = watt + ((size_t)(hh * NB + g)) * HD;
            float s = 0.f;
            #pragma unroll
            for (int c = 0; c < 8; ++c) {
                const int col = c * 16 + q * 4;
                float4 wv = *(const float4*)(wp + col);
                s += vals[c][0] * wv.x + vals[c][1] * wv.y + vals[c][2] * wv.z + vals[c][3] * wv.w;
            }
            s += __shfl_xor(s, 16, 64);
            s += __shfl_xor(s, 32, 64);
            if (q == 0) att[(size_t)hh * NN + node] = s;
        }
    }
    if (STATS) {
        // column sums/sumsq of the 64 rows this block just wrote
        float sarr[8][2];
        #pragma unroll
        for (int c = 0; c < 8; ++c) {
            float s0 = 0.f, q0 = 0.f;
            #pragma unroll
            for (int r = 0; r < 4; ++r) { s0 += vals[c][r]; q0 += vals[c][r] * vals[c][r]; }
            sarr[c][0] = s0; sarr[c][1] = q0;
        }
        // reduce over m (lanes bits 0..3) per (c,r)... need per-column, so reduce vals per r separately
        #pragma unroll
        for (int c = 0; c < 8; ++c) {
            #pragma unroll
            for (int r = 0; r < 4; ++r) {
                float v = vals[c][r];
                float vq = v * v;
                #pragma unroll
                for (int mk = 1; mk <= 8; mk <<= 1) {
                    v  += __shfl_xor(v, mk, 64);
                    vq += __shfl_xor(vq, mk, 64);
                }
                if (m == 0) {
                    credS[w * HD + c * 16 + q * 4 + r] = v;
                    credQ[w * HD + c * 16 + q * 4 + r] = vq;
                }
            }
        }
        __syncthreads();
        if (tid < HD) {
            float s = credS[tid] + credS[HD + tid] + credS[2 * HD + tid] + credS[3 * HD + tid];
            float sq = credQ[tid] + credQ[HD + tid] + credQ[2 * HD + tid] + credQ[3 * HD + tid];
            atomAddF(&colsum[tid], s);
            atomAddF(&colsq[tid], sq);
        }
        (void)sarr;
    }
}

// ---------------- segment softmax ----------------
__global__ __launch_bounds__(256) void k_segsoftmax(const float* __restrict__ att, float* __restrict__ alpha) {
    const int hh = blockIdx.x >> 6, g = blockIdx.x & 63;
    const int t = threadIdx.x;
    const float* a = att + (size_t)hh * NN + g * NPG;
    float* al = alpha + (size_t)hh * NN + g * NPG;
    float v[4]; float mx = -1e30f;
    #pragma unroll
    for (int i = 0; i < 4; ++i) { v[i] = a[t + i * 256]; mx = fmaxf(mx, v[i]); }
    #pragma unroll
    for (int m = 32; m > 0; m >>= 1) mx = fmaxf(mx, __shfl_xor(mx, m, 64));
    __shared__ float redm[4], reds[4];
    if ((t & 63) == 0) redm[t >> 6] = mx;
    __syncthreads();
    mx = fmaxf(fmaxf(redm[0], redm[1]), fmaxf(redm[2], redm[3]));
    float s = 0.f;
    #pragma unroll
    for (int i = 0; i < 4; ++i) { v[i] = __expf(v[i] - mx); s += v[i]; }
    #pragma unroll
    for (int m = 32; m > 0; m >>= 1) s += __shfl_xor(s, m, 64);
    if ((t & 63) == 0) reds[t >> 6] = s;
    __syncthreads();
    s = reds[0] + reds[1] + reds[2] + reds[3];
    float inv = 1.f / s;
    #pragma unroll
    for (int i = 0; i < 4; ++i) al[t + i * 256] = v[i] * inv;
}

// ---------------- mo + x1 = LN(mo + h2) fused ----------------
__global__ __launch_bounds__(256) void k_mo_x1(const float* __restrict__ h2,
                                               const unsigned short* __restrict__ Ufrag,
                                               const float* __restrict__ alpha,
                                               const float* __restrict__ lng, const float* __restrict__ lnb,
                                               float* __restrict__ x1) {
    const int tid = threadIdx.x;
    const int w = tid >> 6, l = tid & 63, q = l >> 4, m = l & 15;
    const int node = blockIdx.x * BM + w * 16 + m;
    bf16x8s a[4];
    #pragma unroll
    for (int ks = 0; ks < 4; ++ks) {
        float4 v0 = *(const float4*)(h2 + (size_t)node * HD + ks * 32 + q * 8);
        float4 v1 = *(const float4*)(h2 + (size_t)node * HD + ks * 32 + q * 8 + 4);
        union { bf16x8s v; unsigned short u[8]; } pk;
        pk.u[0] = f2bf(v0.x); pk.u[1] = f2bf(v0.y); pk.u[2] = f2bf(v0.z); pk.u[3] = f2bf(v0.w);
        pk.u[4] = f2bf(v1.x); pk.u[5] = f2bf(v1.y); pk.u[6] = f2bf(v1.z); pk.u[7] = f2bf(v1.w);
        a[ks] = pk.v;
    }
    f32x4 mo[8] = {};
    #pragma unroll
    for (int hh = 0; hh < 4; ++hh) {
        f32x4 acc[8] = {};
        #pragma unroll
        for (int ks = 0; ks < 4; ++ks) {
            #pragma unroll
            for (int c = 0; c < 8; ++c) {
                bf16x8s b = *(const bf16x8s*)(Ufrag + (size_t)(((hh * 4 + ks) * 8 + c) * 64 + l) * 8);
                acc[c] = MFMA16(b, a[ks], acc[c]);
            }
        }
        float al = alpha[(size_t)hh * NN + node];
        #pragma unroll
        for (int c = 0; c < 8; ++c) {
            mo[c][0] += al * acc[c][0];
            mo[c][1] += al * acc[c][1];
            mo[c][2] += al * acc[c][2];
            mo[c][3] += al * acc[c][3];
        }
    }
    float vals[8][4]; float s = 0.f, sq = 0.f;
    #pragma unroll
    for (int c = 0; c < 8; ++c) {
        const int col = c * 16 + q * 4;
        float4 hv = *(const float4*)(h2 + (size_t)node * HD + col);
        vals[c][0] = mo[c][0] + hv.x;
        vals[c][1] = mo[c][1] + hv.y;
        vals[c][2] = mo[c][2] + hv.z;
        vals[c][3] = mo[c][3] + hv.w;
        #pragma unroll
        for (int r = 0; r < 4; ++r) { s += vals[c][r]; sq += vals[c][r] * vals[c][r]; }
    }
    s  += __shfl_xor(s, 16, 64);  s  += __shfl_xor(s, 32, 64);
    sq += __shfl_xor(sq, 16, 64); sq += __shfl_xor(sq, 32, 64);
    float mean = s * (1.f / HD);
    float var  = sq * (1.f / HD) - mean * mean;
    float rstd = rsqrtf(var + BEPS);
    #pragma unroll
    for (int c = 0; c < 8; ++c) {
        const int col = c * 16 + q * 4;
        float4 gv = *(const float4*)(lng + col);
        float4 bv = *(const float4*)(lnb + col);
        float4 o;
        o.x = (vals[c][0] - mean) * rstd * gv.x + bv.x;
        o.y = (vals[c][1] - mean) * rstd * gv.y + bv.y;
        o.z = (vals[c][2] - mean) * rstd * gv.z + bv.z;
        o.w = (vals[c][3] - mean) * rstd * gv.w + bv.w;
        *(float4*)(x1 + (size_t)node * HD + col) = o;
    }
}

// ---------------- FFN1: mid = bf16(relu(x1 @ Wf1 + bf1)) ----------------
__global__ __launch_bounds__(256) void k_ffn1_mfma(const float* __restrict__ X,
                                                   const unsigned short* __restrict__ Wfrag,
                                                   const float* __restrict__ bias,
                                                   unsigned short* __restrict__ mid) {
    const int tid = threadIdx.x;
    const int w = tid >> 6, l = tid & 63, q = l >> 4, m = l & 15;
    const int node = blockIdx.x * BM + w * 16 + m;
    bf16x8s a[4];
    #pragma unroll
    for (int ks = 0; ks < 4; ++ks) {
        float4 v0 = *(const float4*)(X + (size_t)node * HD + ks * 32 + q * 8);
        float4 v1 = *(const float4*)(X + (size_t)node * HD + ks * 32 + q * 8 + 4);
        union { bf16x8s v; unsigned short u[8]; } pk;
        pk.u[0] = f2bf(v0.x); pk.u[1] = f2bf(v0.y); pk.u[2] = f2bf(v0.z); pk.u[3] = f2bf(v0.w);
        pk.u[4] = f2bf(v1.x); pk.u[5] = f2bf(v1.y); pk.u[6] = f2bf(v1.z); pk.u[7] = f2bf(v1.w);
        a[ks] = pk.v;
    }
    f32x4 acc[16] = {};
    #pragma unroll
    for (int ks = 0; ks < 4; ++ks) {
        #pragma unroll
        for (int c = 0; c < 16; ++c) {
            bf16x8s b = *(const bf16x8s*)(Wfrag + (size_t)((ks * 16 + c) * 64 + l) * 8);
            acc[c] = MFMA16(b, a[ks], acc[c]);
        }
    }
    #pragma unroll
    for (int c = 0; c < 16; ++c) {
        const int col = c * 16 + q * 4;
        float4 bv = *(const float4*)(bias + col);
        ushort4 o;
        o.x = f2bf(fmaxf(acc[c][0] + bv.x, 0.f));
        o.y = f2bf(fmaxf(acc[c][1] + bv.y, 0.f));
        o.z = f2bf(fmaxf(acc[c][2] + bv.z, 0.f));
        o.w = f2bf(fmaxf(acc[c][3] + bv.w, 0.f));
        *(ushort4*)(mid + (size_t)node * HD2 + col) = o;
    }
}

// ---------------- FFN2 + LN + fused graph readout ----------------
__global__ __launch_bounds__(256) void k_ffn2_mfma(const unsigned short* __restrict__ mid,
                                                   const unsigned short* __restrict__ Wfrag,
                                                   const float* __restrict__ bias,
                                                   const float* __restrict__ x1,
                                                   const float* __restrict__ lng, const float* __restrict__ lnb,
                                                   float* __restrict__ outp) {
    __shared__ float cred[4 * HD];
    const int tid = threadIdx.x;
    const int w = tid >> 6, l = tid & 63, q = l >> 4, m = l & 15;
    const int node = blockIdx.x * BM + w * 16 + m;
    bf16x8s a[8];
    #pragma unroll
    for (int ks = 0; ks < 8; ++ks)
        a[ks] = *(const bf16x8s*)(mid + (size_t)node * HD2 + ks * 32 + q * 8);
    f32x4 acc[8] = {};
    #pragma unroll
    for (int ks = 0; ks < 8; ++ks) {
        #pragma unroll
        for (int c = 0; c < 8; ++c) {
            bf16x8s b = *(const bf16x8s*)(Wfrag + (size_t)((ks * 8 + c) * 64 + l) * 8);
            acc[c] = MFMA16(b, a[ks], acc[c]);
        }
    }
    float vals[8][4]; float s = 0.f, sq = 0.f;
    #pragma unroll
    for (int c = 0; c < 8; ++c) {
        const int col = c * 16 + q * 4;
        float4 bv = *(const float4*)(bias + col);
        float4 xv = *(const float4*)(x1 + (size_t)node * HD + col);
        vals[c][0] = acc[c][0] + bv.x + xv.x;
        vals[c][1] = acc[c][1] + bv.y + xv.y;
        vals[c][2] = acc[c][2] + bv.z + xv.z;
        vals[c][3] = acc[c][3] + bv.w + xv.w;
        #pragma unroll
        for (int r = 0; r < 4; ++r) { s += vals[c][r]; sq += vals[c][r] * vals[c][r]; }
    }
    s  += __shfl_xor(s, 16, 64);  s  += __shfl_xor(s, 32, 64);
    sq += __shfl_xor(sq, 16, 64); sq += __shfl_xor(sq, 32, 64);
    float mean = s * (1.f / HD);
    float var  = sq * (1.f / HD) - mean * mean;
    float rstd = rsqrtf(var + BEPS);
    #pragma unroll
    for (int c = 0; c < 8; ++c) {
        const int col = c * 16 + q * 4;
        float4 gv = *(const float4*)(lng + col);
        float4 bv = *(const float4*)(lnb + col);
        float4 o;
        o.x = (vals[c][0] - mean) * rstd * gv.x + bv.x;
        o.y = (vals[c][1] - mean) * rstd * gv.y + bv.y;
        o.z = (vals[c][2] - mean) * rstd * gv.z + bv.z;
        o.w = (vals[c][3] - mean) * rstd * gv.w + bv.w;
        #pragma unroll
        for (int mk = 1; mk <= 8; mk <<= 1) {
            o.x += __shfl_xor(o.x, mk, 64);
            o.y += __shfl_xor(o.y, mk, 64);
            o.z += __shfl_xor(o.z, mk, 64);
            o.w += __shfl_xor(o.w, mk, 64);
        }
        if (m == 0) *(float4*)(cred + w * HD + col) = o;
    }
    __syncthreads();
    if (tid < HD) {
        float sum = cred[tid] + cred[HD + tid] + cred[2 * HD + tid] + cred[3 * HD + tid];
        int g = blockIdx.x >> 4;
        atomAddF(&outp[g * HD + tid], sum);
    }
}

extern "C" void kernel_launch(void* const* d_in, const int* in_sizes, int n_in,
                              void* d_out, int out_size, void* d_ws, size_t ws_size,
                              hipStream_t stream) {
    (void)in_sizes; (void)n_in; (void)out_size;
    const float* h      = (const float*)d_in[0];
    const float* interf = (const float*)d_in[1];
    const float* gamma1 = (const float*)d_in[2];
    const float* beta1  = (const float*)d_in[3];
    const float* W1     = (const float*)d_in[4];
    const float* b1     = (const float*)d_in[5];
    const float* gamma2 = (const float*)d_in[6];
    const float* beta2  = (const float*)d_in[7];
    const float* W2     = (const float*)d_in[8];
    const float* b2     = (const float*)d_in[9];
    const float* Wq     = (const float*)d_in[10];
    const float* Wk     = (const float*)d_in[11];
    const float* Wv     = (const float*)d_in[12];
    const float* Wc     = (const float*)d_in[13];
    const float* ln_g   = (const float*)d_in[14];
    const float* ln_b   = (const float*)d_in[15];
    const float* Wf1    = (const float*)d_in[16];
    const float* bf1    = (const float*)d_in[17];
    const float* Wf2    = (const float*)d_in[18];
    const float* bf2    = (const float*)d_in[19];
    const int*   src    = (const int*)d_in[20];
    const int*   dst    = (const int*)d_in[21];

    float* out = (float*)d_out;              // [0:8192) readout, [8192:16384) init_avg_h
    float* R1 = (float*)d_ws;                // 32MB: (cnt/rank scratch) -> h1 -> x1
    float* R2 = R1 + 8388608;                // 32MB: h2 -> mid(bf16)
    float* R3 = R2 + 8388608;                // 32MB: xn bf16 | agg bf16 ; att/alpha overlay xn
    float* aux = R3 + 8388608;

    float* h1 = R1;
    float* x1 = R1;
    float* h2 = R2;
    unsigned short* mid  = (unsigned short*)R2;
    unsigned short* xn   = (unsigned short*)R3;                 // 16MB
    unsigned short* aggb = (unsigned short*)(R3 + 4194304);     // 16MB
    float* att   = R3;                       // overlays xn (dead by then)
    float* alpha = R3 + 262144;
    int* cnt_o = (int*)R1;                   // early scratch in R1, dead before h1
    int* cnt_i = cnt_o + 65536;
    unsigned short* rank = (unsigned short*)(R1 + 131072);   // 1M ushorts, dead before h1

    float* dout_r  = aux;                    // 65536
    float* din_r   = aux + 65536;            // 65536
    float* colsum1 = aux + 131072;           // 128
    float* colsq1  = aux + 131200;           // 128
    float* colsum2 = aux + 131328;           // 128
    float* colsq2  = aux + 131456;           // 128
    float* watt    = aux + 131584;           // 32768 -> ends 164352
    int*   offs    = (int*)(aux + 164352);   // 65537 -> ends 229889
    int*   elist   = (int*)(aux + 229892);   // 1048576 -> ends 1278468
    unsigned short* W1f  = (unsigned short*)(aux + 1278468);  // 16384 sh
    unsigned short* W2f  = (unsigned short*)(aux + 1286660);
    unsigned short* Wf1f = (unsigned short*)(aux + 1294852);  // 32768 sh
    unsigned short* Wf2f = (unsigned short*)(aux + 1311236);
    unsigned short* Uf   = (unsigned short*)(aux + 1327620);  // 65536 sh -> ends 1360388

    if (ws_size < (size_t)(25165824 + 1360388) * 4) return;

    hipMemsetAsync(out, 0, 16384 * 4, stream);
    hipMemsetAsync(cnt_o, 0, 65536 * 4 * 2, stream);
    hipMemsetAsync(colsum1, 0, 512 * 4, stream);

    k_prep1<<<1024, 256, 0, stream>>>(src, dst, cnt_o, cnt_i, rank);
    k_degfin<<<256, 256, 0, stream>>>(cnt_o, cnt_i, dout_r, din_r);
    k_scan<<<1, 1024, 0, stream>>>(cnt_i, offs);
    k_fill2<<<1024, 256, 0, stream>>>(src, dst, offs, rank, elist);
    k_pool_colstats<<<1024, 128, 0, stream>>>(h, out + 8192, colsum1, colsq1);

    // weight prep
    k_prepW<<<8, 256, 0, stream>>>(W1, W1f, 128, 128);
    k_prepW<<<8, 256, 0, stream>>>(W2, W2f, 128, 128);
    k_prepW<<<16, 256, 0, stream>>>(Wf1, Wf1f, 128, 256);
    k_prepW<<<16, 256, 0, stream>>>(Wf2, Wf2f, 256, 128);
    k_kw<<<256, 128, 0, stream>>>(interf, Wk, Wq, watt);
    k_Ufrag<<<256, 256, 0, stream>>>(Wv, Wc, Uf);

    // gconv block 1 (colstats of h1 fused into epilogue)
    k_bnpack<<<4096, 256, 0, stream>>>(h, colsum1, colsq1, gamma1, beta1, dout_r, xn);
    k_aggregate<<<16384, 256, 0, stream>>>(xn, din_r, offs, elist, aggb);
    k_gconv_mfma<false, true><<<1024, 256, 0, stream>>>(aggb, W1f, b1, h, h1, nullptr, nullptr, colsum2, colsq2);

    // gconv block 2 (+ fused attention scores)
    k_bnpack<<<4096, 256, 0, stream>>>(h1, colsum2, colsq2, gamma2, beta2, dout_r, xn);
    k_aggregate<<<16384, 256, 0, stream>>>(xn, din_r, offs, elist, aggb);
    k_gconv_mfma<true, false><<<1024, 256, 0, stream>>>(aggb, W2f, b2, h1, h2, watt, att, nullptr, nullptr);

    // attention softmax + mo + x1
    k_segsoftmax<<<256, 256, 0, stream>>>(att, alpha);
    k_mo_x1<<<1024, 256, 0, stream>>>(h2, Uf, alpha, ln_g, ln_b, x1);

    // FFN + fused readout
    k_ffn1_mfma<<<1024, 256, 0, stream>>>(x1, Wf1f, bf1, mid);
    k_ffn2_mfma<<<1024, 256, 0, stream>>>(mid, Wf2f, bf2, x1, ln_g, ln_b, out);
}

// Round 5
// 339.613 us; speedup vs baseline: 12.0043x; 1.3732x over previous
//
#include <hip/hip_runtime.h>

#define NN 65536
#define NE 1048576
#define NB 64
#define HD 128
#define HD2 256
#define NHEAD 4
#define NPG 1024
#define BEPS 1e-5f
#define BM 64
#define ESTRIDE 20480   // per-graph edge bucket stride (mean 16384, +32 sigma)

typedef short bf16x8s __attribute__((ext_vector_type(8)));
typedef float f32x4 __attribute__((ext_vector_type(4)));
#define MFMA16(a,b,c) __builtin_amdgcn_mfma_f32_16x16x32_bf16(a,b,c,0,0,0)

__device__ __forceinline__ unsigned short f2bf(float f) {
    union { float f; unsigned int u; } x{f};
    unsigned int r = x.u + 0x7FFFu + ((x.u >> 16) & 1u);
    return (unsigned short)(r >> 16);
}
__device__ __forceinline__ float b2f(unsigned short s) {
    union { unsigned int u; float f; } x{((unsigned int)s) << 16};
    return x.f;
}
__device__ __forceinline__ void atomAddF(float* p, float v) { unsafeAtomicAdd(p, v); }

// ---------------- prep pass 1: bucket edges by graph (LDS-aggregated) + pooling/colstats ----------------
__global__ __launch_bounds__(256) void k_prep_pool(const int* __restrict__ src, const int* __restrict__ dst,
                                                   int* __restrict__ gcurD, int* __restrict__ gcurS,
                                                   unsigned int* __restrict__ dbuck, unsigned short* __restrict__ sbuck,
                                                   const float* __restrict__ h, float* __restrict__ out_avg,
                                                   float* __restrict__ colsum, float* __restrict__ colsq) {
    __shared__ int cntD[64], cntS[64], baseD[64], baseS[64];
    __shared__ float ls[256], lq[256];
    const int t = threadIdx.x;
    if (blockIdx.x < 512) {
        if (t < 64) { cntD[t] = 0; cntS[t] = 0; }
        __syncthreads();
        const int e0 = blockIdx.x * 2048;
        int sv[8], dv[8];
        #pragma unroll
        for (int j = 0; j < 8; ++j) {
            int e = e0 + j * 256 + t;
            sv[j] = src[e]; dv[j] = dst[e];
            atomicAdd(&cntD[dv[j] >> 10], 1);
            atomicAdd(&cntS[sv[j] >> 10], 1);
        }
        __syncthreads();
        if (t < 64) baseD[t] = atomicAdd(&gcurD[t], cntD[t]);
        else if (t < 128) baseS[t - 64] = atomicAdd(&gcurS[t - 64], cntS[t - 64]);
        __syncthreads();
        if (t < 64) { cntD[t] = 0; cntS[t] = 0; }
        __syncthreads();
        #pragma unroll
        for (int j = 0; j < 8; ++j) {
            int gd = dv[j] >> 10;
            int slot = baseD[gd] + atomicAdd(&cntD[gd], 1);
            if (slot < ESTRIDE)
                dbuck[gd * ESTRIDE + slot] = (unsigned)(dv[j] & 1023) | ((unsigned)sv[j] << 10);
            int gs = sv[j] >> 10;
            int slot2 = baseS[gs] + atomicAdd(&cntS[gs], 1);
            if (slot2 < ESTRIDE)
                sbuck[gs * ESTRIDE + slot2] = (unsigned short)(sv[j] & 1023);
        }
    } else {
        int b2 = blockIdx.x - 512;        // 1024 pooling blocks, 64 rows each
        int r0 = b2 * 64;
        int c = t & 127, half = t >> 7;
        float s = 0.f, sq = 0.f;
        for (int r = r0 + half * 32; r < r0 + half * 32 + 32; ++r) {
            float v = h[(size_t)r * HD + c];
            s += v; sq += v * v;
        }
        ls[t] = s; lq[t] = sq;
        __syncthreads();
        if (t < 128) {
            s = ls[t] + ls[t + 128]; sq = lq[t] + lq[t + 128];
            atomAddF(&out_avg[(r0 >> 10) * HD + t], s * (1.0f / NPG));
            atomAddF(&colsum[t], s);
            atomAddF(&colsq[t], sq);
        }
    }
}

// ---------------- prep pass 2: per-graph CSR build + degrees (LDS atomics only) ----------------
__global__ __launch_bounds__(1024) void k_prep2(const int* __restrict__ gcurD, const int* __restrict__ gcurS,
                                                const unsigned int* __restrict__ dbuck,
                                                const unsigned short* __restrict__ sbuck,
                                                float* __restrict__ din_r, float* __restrict__ dout_r,
                                                int* __restrict__ beg, int* __restrict__ endv,
                                                int* __restrict__ elist) {
    __shared__ int hist[1024];
    __shared__ int pre[1024];
    const int t = threadIdx.x;
    const int b = blockIdx.x;
    if (b < 64) {
        const int g = b;
        const int n = min(gcurD[g], ESTRIDE);
        const unsigned int* pd = dbuck + g * ESTRIDE;
        hist[t] = 0;
        __syncthreads();
        for (int i = t; i < n; i += 1024) atomicAdd(&hist[pd[i] & 1023], 1);
        __syncthreads();
        const int cnt = hist[t];
        din_r[g * 1024 + t] = rsqrtf((float)max(cnt, 1));
        int x = cnt; pre[t] = x;
        __syncthreads();
        #pragma unroll
        for (int off = 1; off < 1024; off <<= 1) {
            int v = (t >= off) ? pre[t - off] : 0;
            __syncthreads();
            x += v; pre[t] = x;
            __syncthreads();
        }
        const int excl = x - cnt;
        beg[g * 1024 + t]  = g * ESTRIDE + excl;
        endv[g * 1024 + t] = g * ESTRIDE + excl + cnt;
        __syncthreads();
        hist[t] = excl; pre[t] = 0;
        __syncthreads();
        for (int i = t; i < n; i += 1024) {
            unsigned int w = pd[i];
            int dl = w & 1023;
            int r = atomicAdd(&pre[dl], 1);
            elist[g * ESTRIDE + hist[dl] + r] = (int)(w >> 10);
        }
    } else {
        const int g = b - 64;
        const int m = min(gcurS[g], ESTRIDE);
        const unsigned short* ps = sbuck + g * ESTRIDE;
        hist[t] = 0;
        __syncthreads();
        for (int i = t; i < m; i += 1024) atomicAdd(&hist[ps[i]], 1);
        __syncthreads();
        dout_r[g * 1024 + t] = rsqrtf((float)max(hist[t], 1));
    }
}

// ---------------- fused weight prep: W frags + watt + U frags in one dispatch ----------------
__device__ __forceinline__ void dev_prepW(int idx, const float* __restrict__ W,
                                          unsigned short* __restrict__ frag, int O) {
    int l = idx & 63, tt = idx >> 6;
    int ot = O >> 4;
    int c = tt % ot, ks = tt / ot;
    int q = l >> 4, m = l & 15;
    const float* wp = W + (size_t)(ks * 32 + q * 8) * O + c * 16 + m;
    union { uint4 v; unsigned short u[8]; } pk;
    #pragma unroll
    for (int j = 0; j < 8; ++j) pk.u[j] = f2bf(wp[(size_t)j * O]);
    *(uint4*)(frag + (size_t)idx * 8) = pk.v;
}

__global__ __launch_bounds__(256) void k_wprep(const float* __restrict__ W1, const float* __restrict__ W2,
                                               const float* __restrict__ Wf1, const float* __restrict__ Wf2,
                                               const float* __restrict__ interf, const float* __restrict__ Wk,
                                               const float* __restrict__ Wq, const float* __restrict__ Wv,
                                               const float* __restrict__ Wc,
                                               unsigned short* __restrict__ W1f, unsigned short* __restrict__ W2f,
                                               unsigned short* __restrict__ Wf1f, unsigned short* __restrict__ Wf2f,
                                               float* __restrict__ watt, unsigned short* __restrict__ Uf) {
    const int b = blockIdx.x, t = threadIdx.x;
    if (b < 8)        dev_prepW(b * 256 + t, W1, W1f, 128);
    else if (b < 16)  dev_prepW((b - 8) * 256 + t, W2, W2f, 128);
    else if (b < 32)  dev_prepW((b - 16) * 256 + t, Wf1, Wf1f, 256);
    else if (b < 48)  dev_prepW((b - 32) * 256 + t, Wf2, Wf2f, 128);
    else if (b < 304) {
        int hb = b - 48;                 // h*64+g
        int hh = hb >> 6, g = hb & 63;
        __shared__ float f[HD];
        __shared__ float kv[HD];
        if (t < HD) f[t] = interf[g * HD + t];
        __syncthreads();
        if (t < HD) {
            const float* Wkh = Wk + (size_t)hh * HD * HD;
            float s = 0.f;
            for (int d = 0; d < HD; ++d) s += f[d] * Wkh[(size_t)d * HD + t];
            kv[t] = s;
        }
        __syncthreads();
        if (t < HD) {
            const float* row = Wq + ((size_t)hh * HD + t) * HD;
            float s2 = 0.f;
            #pragma unroll 4
            for (int o = 0; o < HD; o += 4) {
                float4 w = *(const float4*)(row + o);
                s2 += w.x * kv[o] + w.y * kv[o + 1] + w.z * kv[o + 2] + w.w * kv[o + 3];
            }
            watt[hb * HD + t] = s2 * 0.027950849718747373f;   // 1/sqrt(1280)
        }
    } else {
        int idx = (b - 304) * 256 + t;   // 65536 total
        int o = idx & 127;
        int d = (idx >> 7) & 127;
        int hh = idx >> 14;
        const float* wv = Wv + ((size_t)hh * HD + d) * HD;
        const float* wc = Wc + (size_t)(hh * HD) * HD + o;
        float s = 0.f;
        for (int m2 = 0; m2 < HD; ++m2) s += wv[m2] * wc[(size_t)m2 * HD];
        int ks = d >> 5, dd = d & 31, q = dd >> 3, j = dd & 7;
        int c = o >> 4, m = o & 15, l = q * 16 + m;
        Uf[(size_t)((((hh * 4 + ks) * 8 + c) * 64 + l) * 8 + j)] = f2bf(s);
    }
}

// ---------------- bnpack (inline BN params): xn = bf16((x*sc+sh)*dout_r) ----------------
__global__ __launch_bounds__(256) void k_bnpack(const float* __restrict__ x,
                                                const float* __restrict__ colsum, const float* __restrict__ colsq,
                                                const float* __restrict__ gma, const float* __restrict__ bta,
                                                const float* __restrict__ dout_r, unsigned short* __restrict__ xn) {
    int idx = blockIdx.x * 256 + threadIdx.x;     // N*16 threads, 8 elems each
    int node = idx >> 4;
    int c8 = (idx & 15) * 8;
    float sc[8], sh[8];
    #pragma unroll
    for (int j = 0; j < 8; ++j) {
        float mean = colsum[c8 + j] * (1.0f / NN);
        float var  = colsq[c8 + j] * (1.0f / NN) - mean * mean;
        float rstd = rsqrtf(var + BEPS);
        sc[j] = rstd * gma[c8 + j];
        sh[j] = bta[c8 + j] - mean * sc[j];
    }
    float dr = dout_r[node];
    float4 v0 = *(const float4*)(x + (size_t)node * HD + c8);
    float4 v1 = *(const float4*)(x + (size_t)node * HD + c8 + 4);
    union { uint4 v; unsigned short u[8]; } pk;
    pk.u[0] = f2bf((v0.x * sc[0] + sh[0]) * dr);
    pk.u[1] = f2bf((v0.y * sc[1] + sh[1]) * dr);
    pk.u[2] = f2bf((v0.z * sc[2] + sh[2]) * dr);
    pk.u[3] = f2bf((v0.w * sc[3] + sh[3]) * dr);
    pk.u[4] = f2bf((v1.x * sc[4] + sh[4]) * dr);
    pk.u[5] = f2bf((v1.y * sc[5] + sh[5]) * dr);
    pk.u[6] = f2bf((v1.z * sc[6] + sh[6]) * dr);
    pk.u[7] = f2bf((v1.w * sc[7] + sh[7]) * dr);
    *(uint4*)(xn + (size_t)node * HD + c8) = pk.v;
}

// ---------------- CSR aggregation: wave per node, 4-edge ILP ----------------
__global__ __launch_bounds__(256) void k_aggregate(const unsigned short* __restrict__ xn,
                                                   const float* __restrict__ din_r,
                                                   const int* __restrict__ beg, const int* __restrict__ endv,
                                                   const int* __restrict__ elist,
                                                   unsigned short* __restrict__ agg) {
    const int tid = threadIdx.x;
    const int node = blockIdx.x * 4 + (tid >> 6);
    const int c2 = (tid & 63) * 2;
    const int b0 = beg[node], e0 = endv[node];
    float a0 = 0.f, a1 = 0.f;
    int i = b0;
    for (; i + 4 <= e0; i += 4) {
        int s0 = elist[i], s1 = elist[i + 1], s2 = elist[i + 2], s3 = elist[i + 3];
        unsigned int v0 = *(const unsigned int*)(xn + (size_t)s0 * HD + c2);
        unsigned int v1 = *(const unsigned int*)(xn + (size_t)s1 * HD + c2);
        unsigned int v2 = *(const unsigned int*)(xn + (size_t)s2 * HD + c2);
        unsigned int v3 = *(const unsigned int*)(xn + (size_t)s3 * HD + c2);
        a0 += b2f((unsigned short)v0) + b2f((unsigned short)v1) + b2f((unsigned short)v2) + b2f((unsigned short)v3);
        a1 += b2f((unsigned short)(v0 >> 16)) + b2f((unsigned short)(v1 >> 16))
            + b2f((unsigned short)(v2 >> 16)) + b2f((unsigned short)(v3 >> 16));
    }
    for (; i < e0; ++i) {
        int s = elist[i];
        unsigned int v = *(const unsigned int*)(xn + (size_t)s * HD + c2);
        a0 += b2f((unsigned short)v);
        a1 += b2f((unsigned short)(v >> 16));
    }
    float dn = din_r[node];
    ushort2 o;
    o.x = f2bf(a0 * dn); o.y = f2bf(a1 * dn);
    *(ushort2*)(agg + (size_t)node * HD + c2) = o;
}

// ---------------- gconv MFMA: out = res + relu(agg @ W + b); fused scores / colstats ----------------
template<bool SCORES, bool STATS>
__global__ __launch_bounds__(256) void k_gconv_mfma(const unsigned short* __restrict__ agg,
                                                    const unsigned short* __restrict__ Wfrag,
                                                    const float* __restrict__ bias,
                                                    const float* __restrict__ res, float* __restrict__ outp,
                                                    const float* __restrict__ watt, float* __restrict__ att,
                                                    float* __restrict__ colsum, float* __restrict__ colsq) {
    __shared__ float credS[4 * HD];
    __shared__ float credQ[4 * HD];
    const int tid = threadIdx.x;
    const int w = tid >> 6, l = tid & 63, q = l >> 4, m = l & 15;
    const int node = blockIdx.x * BM + w * 16 + m;
    bf16x8s a[4];
    #pragma unroll
    for (int ks = 0; ks < 4; ++ks)
        a[ks] = *(const bf16x8s*)(agg + (size_t)node * HD + ks * 32 + q * 8);
    f32x4 acc[8] = {};
    #pragma unroll
    for (int ks = 0; ks < 4; ++ks) {
        #pragma unroll
        for (int c = 0; c < 8; ++c) {
            bf16x8s b = *(const bf16x8s*)(Wfrag + (size_t)((ks * 8 + c) * 64 + l) * 8);
            acc[c] = MFMA16(b, a[ks], acc[c]);
        }
    }
    float vals[8][4];
    #pragma unroll
    for (int c = 0; c < 8; ++c) {
        const int col = c * 16 + q * 4;
        float4 bv = *(const float4*)(bias + col);
        float4 rv = *(const float4*)(res + (size_t)node * HD + col);
        vals[c][0] = rv.x + fmaxf(acc[c][0] + bv.x, 0.f);
        vals[c][1] = rv.y + fmaxf(acc[c][1] + bv.y, 0.f);
        vals[c][2] = rv.z + fmaxf(acc[c][2] + bv.z, 0.f);
        vals[c][3] = rv.w + fmaxf(acc[c][3] + bv.w, 0.f);
        *(float4*)(outp + (size_t)node * HD + col) = make_float4(vals[c][0], vals[c][1], vals[c][2], vals[c][3]);
    }
    if (SCORES) {
        const int g = node >> 10;
        #pragma unroll
        for (int hh = 0; hh < NHEAD; ++hh) {
            const float* wp = watt + ((size_t)(hh * NB + g)) * HD;
            float s = 0.f;
            #pragma unroll
            for (int c = 0; c < 8; ++c) {
                const int col = c * 16 + q * 4;
                float4 wv = *(const float4*)(wp + col);
                s += vals[c][0] * wv.x + vals[c][1] * wv.y + vals[c][2] * wv.z + vals[c][3] * wv.w;
            }
            s += __shfl_xor(s, 16, 64);
            s += __shfl_xor(s, 32, 64);
            if (q == 0) att[(size_t)hh * NN + node] = s;
        }
    }
    if (STATS) {
        #pragma unroll
        for (int c = 0; c < 8; ++c) {
            #pragma unroll
            for (int r = 0; r < 4; ++r) {
                float v = vals[c][r];
                float vq = v * v;
                #pragma unroll
                for (int mk = 1; mk <= 8; mk <<= 1) {
                    v  += __shfl_xor(v, mk, 64);
                    vq += __shfl_xor(vq, mk, 64);
                }
                if (m == 0) {
                    credS[w * HD + c * 16 + q * 4 + r] = v;
                    credQ[w * HD + c * 16 + q * 4 + r] = vq;
                }
            }
        }
        __syncthreads();
        if (tid < HD) {
            float s = credS[tid] + credS[HD + tid] + credS[2 * HD + tid] + credS[3 * HD + tid];
            float sq = credQ[tid] + credQ[HD + tid] + credQ[2 * HD + tid] + credQ[3 * HD + tid];
            atomAddF(&colsum[tid], s);
            atomAddF(&colsq[tid], sq);
        }
    }
}

// ---------------- segment softmax ----------------
__global__ __launch_bounds__(256) void k_segsoftmax(const float* __restrict__ att, float* __restrict__ alpha) {
    const int hh = blockIdx.x >> 6, g = blockIdx.x & 63;
    const int t = threadIdx.x;
    const float* a = att + (size_t)hh * NN + g * NPG;
    float* al = alpha + (size_t)hh * NN + g * NPG;
    float v[4]; float mx = -1e30f;
    #pragma unroll
    for (int i = 0; i < 4; ++i) { v[i] = a[t + i * 256]; mx = fmaxf(mx, v[i]); }
    #pragma unroll
    for (int m = 32; m > 0; m >>= 1) mx = fmaxf(mx, __shfl_xor(mx, m, 64));
    __shared__ float redm[4], reds[4];
    if ((t & 63) == 0) redm[t >> 6] = mx;
    __syncthreads();
    mx = fmaxf(fmaxf(redm[0], redm[1]), fmaxf(redm[2], redm[3]));
    float s = 0.f;
    #pragma unroll
    for (int i = 0; i < 4; ++i) { v[i] = __expf(v[i] - mx); s += v[i]; }
    #pragma unroll
    for (int m = 32; m > 0; m >>= 1) s += __shfl_xor(s, m, 64);
    if ((t & 63) == 0) reds[t >> 6] = s;
    __syncthreads();
    s = reds[0] + reds[1] + reds[2] + reds[3];
    float inv = 1.f / s;
    #pragma unroll
    for (int i = 0; i < 4; ++i) al[t + i * 256] = v[i] * inv;
}

// ---------------- mo + x1 = LN(mo + h2) fused ----------------
__global__ __launch_bounds__(256) void k_mo_x1(const float* __restrict__ h2,
                                               const unsigned short* __restrict__ Ufrag,
                                               const float* __restrict__ alpha,
                                               const float* __restrict__ lng, const float* __restrict__ lnb,
                                               float* __restrict__ x1) {
    const int tid = threadIdx.x;
    const int w = tid >> 6, l = tid & 63, q = l >> 4, m = l & 15;
    const int node = blockIdx.x * BM + w * 16 + m;
    bf16x8s a[4];
    #pragma unroll
    for (int ks = 0; ks < 4; ++ks) {
        float4 v0 = *(const float4*)(h2 + (size_t)node * HD + ks * 32 + q * 8);
        float4 v1 = *(const float4*)(h2 + (size_t)node * HD + ks * 32 + q * 8 + 4);
        union { bf16x8s v; unsigned short u[8]; } pk;
        pk.u[0] = f2bf(v0.x); pk.u[1] = f2bf(v0.y); pk.u[2] = f2bf(v0.z); pk.u[3] = f2bf(v0.w);
        pk.u[4] = f2bf(v1.x); pk.u[5] = f2bf(v1.y); pk.u[6] = f2bf(v1.z); pk.u[7] = f2bf(v1.w);
        a[ks] = pk.v;
    }
    f32x4 mo[8] = {};
    #pragma unroll
    for (int hh = 0; hh < 4; ++hh) {
        f32x4 acc[8] = {};
        #pragma unroll
        for (int ks = 0; ks < 4; ++ks) {
            #pragma unroll
            for (int c = 0; c < 8; ++c) {
                bf16x8s b = *(const bf16x8s*)(Ufrag + (size_t)(((hh * 4 + ks) * 8 + c) * 64 + l) * 8);
                acc[c] = MFMA16(b, a[ks], acc[c]);
            }
        }
        float al = alpha[(size_t)hh * NN + node];
        #pragma unroll
        for (int c = 0; c < 8; ++c) {
            mo[c][0] += al * acc[c][0];
            mo[c][1] += al * acc[c][1];
            mo[c][2] += al * acc[c][2];
            mo[c][3] += al * acc[c][3];
        }
    }
    float vals[8][4]; float s = 0.f, sq = 0.f;
    #pragma unroll
    for (int c = 0; c < 8; ++c) {
        const int col = c * 16 + q * 4;
        float4 hv = *(const float4*)(h2 + (size_t)node * HD + col);
        vals[c][0] = mo[c][0] + hv.x;
        vals[c][1] = mo[c][1] + hv.y;
        vals[c][2] = mo[c][2] + hv.z;
        vals[c][3] = mo[c][3] + hv.w;
        #pragma unroll
        for (int r = 0; r < 4; ++r) { s += vals[c][r]; sq += vals[c][r] * vals[c][r]; }
    }
    s  += __shfl_xor(s, 16, 64);  s  += __shfl_xor(s, 32, 64);
    sq += __shfl_xor(sq, 16, 64); sq += __shfl_xor(sq, 32, 64);
    float mean = s * (1.f / HD);
    float var  = sq * (1.f / HD) - mean * mean;
    float rstd = rsqrtf(var + BEPS);
    #pragma unroll
    for (int c = 0; c < 8; ++c) {
        const int col = c * 16 + q * 4;
        float4 gv = *(const float4*)(lng + col);
        float4 bv = *(const float4*)(lnb + col);
        float4 o;
        o.x = (vals[c][0] - mean) * rstd * gv.x + bv.x;
        o.y = (vals[c][1] - mean) * rstd * gv.y + bv.y;
        o.z = (vals[c][2] - mean) * rstd * gv.z + bv.z;
        o.w = (vals[c][3] - mean) * rstd * gv.w + bv.w;
        *(float4*)(x1 + (size_t)node * HD + col) = o;
    }
}

// ---------------- FFN1: mid = bf16(relu(x1 @ Wf1 + bf1)) ----------------
__global__ __launch_bounds__(256) void k_ffn1_mfma(const float* __restrict__ X,
                                                   const unsigned short* __restrict__ Wfrag,
                                                   const float* __restrict__ bias,
                                                   unsigned short* __restrict__ mid) {
    const int tid = threadIdx.x;
    const int w = tid >> 6, l = tid & 63, q = l >> 4, m = l & 15;
    const int node = blockIdx.x * BM + w * 16 + m;
    bf16x8s a[4];
    #pragma unroll
    for (int ks = 0; ks < 4; ++ks) {
        float4 v0 = *(const float4*)(X + (size_t)node * HD + ks * 32 + q * 8);
        float4 v1 = *(const float4*)(X + (size_t)node * HD + ks * 32 + q * 8 + 4);
        union { bf16x8s v; unsigned short u[8]; } pk;
        pk.u[0] = f2bf(v0.x); pk.u[1] = f2bf(v0.y); pk.u[2] = f2bf(v0.z); pk.u[3] = f2bf(v0.w);
        pk.u[4] = f2bf(v1.x); pk.u[5] = f2bf(v1.y); pk.u[6] = f2bf(v1.z); pk.u[7] = f2bf(v1.w);
        a[ks] = pk.v;
    }
    f32x4 acc[16] = {};
    #pragma unroll
    for (int ks = 0; ks < 4; ++ks) {
        #pragma unroll
        for (int c = 0; c < 16; ++c) {
            bf16x8s b = *(const bf16x8s*)(Wfrag + (size_t)((ks * 16 + c) * 64 + l) * 8);
            acc[c] = MFMA16(b, a[ks], acc[c]);
        }
    }
    #pragma unroll
    for (int c = 0; c < 16; ++c) {
        const int col = c * 16 + q * 4;
        float4 bv = *(const float4*)(bias + col);
        ushort4 o;
        o.x = f2bf(fmaxf(acc[c][0] + bv.x, 0.f));
        o.y = f2bf(fmaxf(acc[c][1] + bv.y, 0.f));
        o.z = f2bf(fmaxf(acc[c][2] + bv.z, 0.f));
        o.w = f2bf(fmaxf(acc[c][3] + bv.w, 0.f));
        *(ushort4*)(mid + (size_t)node * HD2 + col) = o;
    }
}

// ---------------- FFN2 + LN + fused graph readout ----------------
__global__ __launch_bounds__(256) void k_ffn2_mfma(const unsigned short* __restrict__ mid,
                                                   const unsigned short* __restrict__ Wfrag,
                                                   const float* __restrict__ bias,
                                                   const float* __restrict__ x1,
                                                   const float* __restrict__ lng, const float* __restrict__ lnb,
                                                   float* __restrict__ outp) {
    __shared__ float cred[4 * HD];
    const int tid = threadIdx.x;
    const int w = tid >> 6, l = tid & 63, q = l >> 4, m = l & 15;
    const int node = blockIdx.x * BM + w * 16 + m;
    bf16x8s a[8];
    #pragma unroll
    for (int ks = 0; ks < 8; ++ks)
        a[ks] = *(const bf16x8s*)(mid + (size_t)node * HD2 + ks * 32 + q * 8);
    f32x4 acc[8] = {};
    #pragma unroll
    for (int ks = 0; ks < 8; ++ks) {
        #pragma unroll
        for (int c = 0; c < 8; ++c) {
            bf16x8s b = *(const bf16x8s*)(Wfrag + (size_t)((ks * 8 + c) * 64 + l) * 8);
            acc[c] = MFMA16(b, a[ks], acc[c]);
        }
    }
    float vals[8][4]; float s = 0.f, sq = 0.f;
    #pragma unroll
    for (int c = 0; c < 8; ++c) {
        const int col = c * 16 + q * 4;
        float4 bv = *(const float4*)(bias + col);
        float4 xv = *(const float4*)(x1 + (size_t)node * HD + col);
        vals[c][0] = acc[c][0] + bv.x + xv.x;
        vals[c][1] = acc[c][1] + bv.y + xv.y;
        vals[c][2] = acc[c][2] + bv.z + xv.z;
        vals[c][3] = acc[c][3] + bv.w + xv.w;
        #pragma unroll
        for (int r = 0; r < 4; ++r) { s += vals[c][r]; sq += vals[c][r] * vals[c][r]; }
    }
    s  += __shfl_xor(s, 16, 64);  s  += __shfl_xor(s, 32, 64);
    sq += __shfl_xor(sq, 16, 64); sq += __shfl_xor(sq, 32, 64);
    float mean = s * (1.f / HD);
    float var  = sq * (1.f / HD) - mean * mean;
    float rstd = rsqrtf(var + BEPS);
    #pragma unroll
    for (int c = 0; c < 8; ++c) {
        const int col = c * 16 + q * 4;
        float4 gv = *(const float4*)(lng + col);
        float4 bv = *(const float4*)(lnb + col);
        float4 o;
        o.x = (vals[c][0] - mean) * rstd * gv.x + bv.x;
        o.y = (vals[c][1] - mean) * rstd * gv.y + bv.y;
        o.z = (vals[c][2] - mean) * rstd * gv.z + bv.z;
        o.w = (vals[c][3] - mean) * rstd * gv.w + bv.w;
        #pragma unroll
        for (int mk = 1; mk <= 8; mk <<= 1) {
            o.x += __shfl_xor(o.x, mk, 64);
            o.y += __shfl_xor(o.y, mk, 64);
            o.z += __shfl_xor(o.z, mk, 64);
            o.w += __shfl_xor(o.w, mk, 64);
        }
        if (m == 0) *(float4*)(cred + w * HD + col) = o;
    }
    __syncthreads();
    if (tid < HD) {
        float sum = cred[tid] + cred[HD + tid] + cred[2 * HD + tid] + cred[3 * HD + tid];
        int g = blockIdx.x >> 4;
        atomAddF(&outp[g * HD + tid], sum);
    }
}

extern "C" void kernel_launch(void* const* d_in, const int* in_sizes, int n_in,
                              void* d_out, int out_size, void* d_ws, size_t ws_size,
                              hipStream_t stream) {
    (void)in_sizes; (void)n_in; (void)out_size;
    const float* h      = (const float*)d_in[0];
    const float* interf = (const float*)d_in[1];
    const float* gamma1 = (const float*)d_in[2];
    const float* beta1  = (const float*)d_in[3];
    const float* W1     = (const float*)d_in[4];
    const float* b1     = (const float*)d_in[5];
    const float* gamma2 = (const float*)d_in[6];
    const float* beta2  = (const float*)d_in[7];
    const float* W2     = (const float*)d_in[8];
    const float* b2     = (const float*)d_in[9];
    const float* Wq     = (const float*)d_in[10];
    const float* Wk     = (const float*)d_in[11];
    const float* Wv     = (const float*)d_in[12];
    const float* Wc     = (const float*)d_in[13];
    const float* ln_g   = (const float*)d_in[14];
    const float* ln_b   = (const float*)d_in[15];
    const float* Wf1    = (const float*)d_in[16];
    const float* bf1    = (const float*)d_in[17];
    const float* Wf2    = (const float*)d_in[18];
    const float* bf2    = (const float*)d_in[19];
    const int*   src    = (const int*)d_in[20];
    const int*   dst    = (const int*)d_in[21];

    float* out = (float*)d_out;              // [0:8192) readout, [8192:16384) init_avg_h
    float* R1 = (float*)d_ws;                // 32MB: dbuck/sbuck -> h1 -> x1
    float* R2 = R1 + 8388608;                // 32MB: elist -> h2 -> mid(bf16)
    float* R3 = R2 + 8388608;                // 32MB: xn bf16 | agg bf16 ; att/alpha overlay xn
    float* aux = R3 + 8388608;

    float* h1 = R1;
    float* x1 = R1;
    unsigned int*   dbuck = (unsigned int*)R1;               // 64*20480 u32 (dead before h1)
    unsigned short* sbuck = (unsigned short*)(R1 + 1310720); // 64*20480 u16 (dead before h1)
    float* h2 = R2;
    int*   elist = (int*)R2;                                 // 64*20480 int (dead before h2)
    unsigned short* mid  = (unsigned short*)R2;
    unsigned short* xn   = (unsigned short*)R3;              // 16MB
    unsigned short* aggb = (unsigned short*)(R3 + 4194304);  // 16MB
    float* att   = R3;                       // overlays xn (dead by then)
    float* alpha = R3 + 262144;

    float* dout_r  = aux;                    // 65536
    float* din_r   = aux + 65536;            // 65536
    float* colsum1 = aux + 131072;           // 128
    float* colsq1  = aux + 131200;
    float* colsum2 = aux + 131328;
    float* colsq2  = aux + 131456;
    int*   gcurD   = (int*)(aux + 131584);   // 64
    int*   gcurS   = (int*)(aux + 131648);   // 64
    float* watt    = aux + 131712;           // 32768 -> 164480
    int*   beg     = (int*)(aux + 164480);   // 65536 -> 230016
    int*   endv    = (int*)(aux + 230016);   // 65536 -> 295552
    unsigned short* W1f  = (unsigned short*)(aux + 295552);  // 16384 sh
    unsigned short* W2f  = (unsigned short*)(aux + 303744);
    unsigned short* Wf1f = (unsigned short*)(aux + 311936);  // 32768 sh
    unsigned short* Wf2f = (unsigned short*)(aux + 328320);
    unsigned short* Uf   = (unsigned short*)(aux + 344704);  // 65536 sh -> ends 377472

    if (ws_size < (size_t)(25165824 + 377472) * 4) return;

    hipMemsetAsync(out, 0, 16384 * 4, stream);
    hipMemsetAsync(colsum1, 0, 640 * 4, stream);   // colsums + gcurD + gcurS (contiguous)

    k_prep_pool<<<1536, 256, 0, stream>>>(src, dst, gcurD, gcurS, dbuck, sbuck,
                                          h, out + 8192, colsum1, colsq1);
    k_prep2<<<128, 1024, 0, stream>>>(gcurD, gcurS, dbuck, sbuck, din_r, dout_r, beg, endv, elist);
    k_wprep<<<560, 256, 0, stream>>>(W1, W2, Wf1, Wf2, interf, Wk, Wq, Wv, Wc,
                                     W1f, W2f, Wf1f, Wf2f, watt, Uf);

    // gconv block 1 (colstats of h1 fused into epilogue)
    k_bnpack<<<4096, 256, 0, stream>>>(h, colsum1, colsq1, gamma1, beta1, dout_r, xn);
    k_aggregate<<<16384, 256, 0, stream>>>(xn, din_r, beg, endv, elist, aggb);
    k_gconv_mfma<false, true><<<1024, 256, 0, stream>>>(aggb, W1f, b1, h, h1, nullptr, nullptr, colsum2, colsq2);

    // gconv block 2 (+ fused attention scores)
    k_bnpack<<<4096, 256, 0, stream>>>(h1, colsum2, colsq2, gamma2, beta2, dout_r, xn);
    k_aggregate<<<16384, 256, 0, stream>>>(xn, din_r, beg, endv, elist, aggb);
    k_gconv_mfma<true, false><<<1024, 256, 0, stream>>>(aggb, W2f, b2, h1, h2, watt, att, nullptr, nullptr);

    // attention softmax + mo + x1
    k_segsoftmax<<<256, 256, 0, stream>>>(att, alpha);
    k_mo_x1<<<1024, 256, 0, stream>>>(h2, Uf, alpha, ln_g, ln_b, x1);

    // FFN + fused readout
    k_ffn1_mfma<<<1024, 256, 0, stream>>>(x1, Wf1f, bf1, mid);
    k_ffn2_mfma<<<1024, 256, 0, stream>>>(mid, Wf2f, bf2, x1, ln_g, ln_b, out);
}